// Round 5
// baseline (1571.437 us; speedup 1.0000x reference)
//
#include <hip/hip_runtime.h>
#include <hip/hip_bf16.h>
#include <stdint.h>

// Swin windowed MHA: N=32, H=W=64, C=512, heads=16, head_dim=32, window 8x8 (E=64).
// conv x->bf16 ; transpose weights ; k_win (fused QKV-proj + windowed attention,
// 1 block/window, barrier-free proj with B from L2) ; GEMM2 (256^2 8-phase, r3 version).

typedef __attribute__((ext_vector_type(4))) float  f32x4;
typedef __attribute__((ext_vector_type(4))) float  fvec4;
typedef __attribute__((ext_vector_type(8))) short  s16x8;
typedef __attribute__((ext_vector_type(8))) __bf16 bf16x8;
typedef __attribute__((ext_vector_type(2))) unsigned int u32x2;
typedef __attribute__((ext_vector_type(4))) unsigned int u32x4;
typedef unsigned short u16;
typedef unsigned int   u32;
typedef __attribute__((ext_vector_type(4))) u16 u16x4;

__device__ __forceinline__ u16 f2bf(float f) {
  u32 u = __builtin_bit_cast(u32, f);
  u32 r = (u + 0x7FFFu + ((u >> 16) & 1u)) >> 16;
  return (u16)r;
}
__device__ __forceinline__ u32 pk2(float x, float y) {
  return (u32)f2bf(x) | ((u32)f2bf(y) << 16);
}

__device__ __forceinline__ f32x4 mfma16(s16x8 a, s16x8 b, f32x4 c) {
  return __builtin_amdgcn_mfma_f32_16x16x32_bf16((bf16x8)a, (bf16x8)b, c, 0, 0, 0);
}

__device__ __forceinline__ void gload16(const u16* g, u16* l) {
  __builtin_amdgcn_global_load_lds(
      (const __attribute__((address_space(1))) u32*)g,
      (__attribute__((address_space(3))) u32*)l, 16, 0, 0);
}

#define BARRIER() asm volatile("s_barrier" ::: "memory")

// ---------------- conversion kernels ----------------
__global__ void k_conv_x(const float* __restrict__ x, u16* __restrict__ xb, int n4) {
  int i = blockIdx.x * 256 + threadIdx.x;
  if (i >= n4) return;
  fvec4 v = ((const fvec4*)x)[i];
  u16x4 o;
  o.x = f2bf(v.x); o.y = f2bf(v.y); o.z = f2bf(v.z); o.w = f2bf(v.w);
  ((u16x4*)xb)[i] = o;
}

__global__ void k_transpose_w(const float* __restrict__ w, u16* __restrict__ wt, int K, int N) {
  int i = blockIdx.x * 256 + threadIdx.x;
  if (i >= K * N) return;
  int k = i / N, n = i - k * N;
  wt[n * K + k] = f2bf(w[i]);
}

// ---------------- fused window kernel ----------------
// 1 block = 1 window (2048 blocks), 512 thr = 8 waves, wave w owns heads {2w, 2w+1}.
// LDS: A = x-window [64 rows][512] bf16 (64KB, chunk-swizzled) at [0,32768) u16;
//      per-wave scratch 4096 u16 (8KB) at 32768 + wid*4096: Q[64][32] + K[64][32],
//      P[64][64] overlays Q+K. V never touches LDS (C-frag -> B-frag via shuffles).
// Barriers: exactly one (after A staging). Proj B-frags read direct from wqkvT (L2).
__global__ __launch_bounds__(512, 2)
void k_win(const u16* __restrict__ xb, const u16* __restrict__ wqkvT,
           const float* __restrict__ qkv_b, const float* __restrict__ mask,
           const float* __restrict__ btab, u16* __restrict__ AO) {
  __shared__ u16 lds[65536];  // 128 KiB
  const int tid = threadIdx.x;
  const int lane = tid & 63, wid = tid >> 6;
  const int quad = lane >> 4, col_l = lane & 15;
  const int win = blockIdx.x;
  const int nimg = win >> 6, a = (win >> 3) & 7, b = win & 7;

  // ---- stage A: row r = g*8+wid, chunk = lane, src chunk pre-swizzled ^ (r&7)=wid
#pragma unroll
  for (int g = 0; g < 8; ++g) {
    const int h = a * 8 + g, w = b * 8 + wid;
    const size_t m = (size_t)nimg * 4096 + h * 64 + w;
    gload16(xb + m * 512 + ((lane ^ wid) * 8), &lds[(g * 512 + tid) * 8]);
  }
  asm volatile("s_waitcnt vmcnt(0)" ::: "memory");
  BARRIER();

  u16* sq = &lds[32768 + wid * 4096];  // Q [64][32] swizzled
  u16* sk = sq + 2048;                 // K [64][32] swizzled
  u16* sp = sq;                        // P [64][64] swizzled (overlays Q+K)

  const float scale = 0.17677669529663687f;  // 1/sqrt(32)
  const float* mrow = mask + (size_t)(a * 8 + b) * 4096;

#pragma unroll 1
  for (int hh = 0; hh < 2; ++hh) {
    const int head = wid * 2 + hh;
    const float qb0 = qkv_b[head * 32 + col_l],        qb1 = qkv_b[head * 32 + 16 + col_l];
    const float kb0 = qkv_b[512 + head * 32 + col_l],  kb1 = qkv_b[512 + head * 32 + 16 + col_l];
    const float vb0 = qkv_b[1024 + head * 32 + col_l], vb1 = qkv_b[1024 + head * 32 + 16 + col_l];

    // ---- proj for this head: acc[mf][nf], nf = {q0,q1,k0,k1,v0,v1}
    f32x4 acc[4][6] = {};
    const u16* bp[6];
#pragma unroll
    for (int nf = 0; nf < 6; ++nf)
      bp[nf] = wqkvT + (size_t)((nf >> 1) * 512 + head * 32 + (nf & 1) * 16 + col_l) * 512;

#pragma unroll 1
    for (int kt = 0; kt < 16; ++kt) {
      s16x8 bf[6], af[4];
#pragma unroll
      for (int nf = 0; nf < 6; ++nf)
        bf[nf] = *(const s16x8*)&bp[nf][kt * 32 + quad * 8];
#pragma unroll
      for (int mf = 0; mf < 4; ++mf)
        af[mf] = *(const s16x8*)&lds[(mf * 16 + col_l) * 512 + (((kt * 4 + quad) ^ (col_l & 7)) * 8)];
#pragma unroll
      for (int mf = 0; mf < 4; ++mf)
#pragma unroll
        for (int nf = 0; nf < 6; ++nf)
          acc[mf][nf] = mfma16(af[mf], bf[nf], acc[mf][nf]);
    }

    // ---- write Q (scaled+bias) and K (bias) to scratch: [e][d], chunk ^= (e>>1)&3
#pragma unroll
    for (int r = 0; r < 4; ++r)
#pragma unroll
      for (int half = 0; half < 2; ++half)
#pragma unroll
        for (int i = 0; i < 4; ++i) {
          const int e = r * 16 + quad * 4 + i;
          const int d = half * 16 + col_l;
          const int sw = (((d >> 3) ^ ((e >> 1) & 3)) << 3) + (d & 7);
          sq[e * 32 + sw] = f2bf((acc[r][half][i] + (half ? qb1 : qb0)) * scale);
          sk[e * 32 + sw] = f2bf(acc[r][2 + half][i] + (half ? kb1 : kb0));
        }

    // ---- S = Q K^T
    s16x8 aq[4], bk[4];
    const int ssw = (quad ^ ((col_l >> 1) & 3)) << 3;
#pragma unroll
    for (int t = 0; t < 4; ++t) {
      aq[t] = *(const s16x8*)&sq[(t * 16 + col_l) * 32 + ssw];
      bk[t] = *(const s16x8*)&sk[(t * 16 + col_l) * 32 + ssw];
    }
    f32x4 s[4][4] = {};
#pragma unroll
    for (int r = 0; r < 4; ++r)
#pragma unroll
      for (int c = 0; c < 4; ++c)
        s[r][c] = mfma16(aq[r], bk[c], s[r][c]);

    // ---- bias + mask
#pragma unroll
    for (int r = 0; r < 4; ++r)
#pragma unroll
      for (int c = 0; c < 4; ++c)
#pragma unroll
        for (int i = 0; i < 4; ++i) {
          const int row = r * 16 + quad * 4 + i, col = c * 16 + col_l;
          const int dh = (row >> 3) - (col >> 3) + 7;
          const int dw = (row & 7) - (col & 7) + 7;
          s[r][c][i] += btab[(dh * 15 + dw) * 16 + head] + mrow[row * 64 + col];
        }

    // ---- softmax (deferred 1/sum)
    float rinv[4][4];
#pragma unroll
    for (int r = 0; r < 4; ++r) {
#pragma unroll
      for (int i = 0; i < 4; ++i) {
        float mx = fmaxf(fmaxf(s[r][0][i], s[r][1][i]), fmaxf(s[r][2][i], s[r][3][i]));
        mx = fmaxf(mx, __shfl_xor(mx, 1));
        mx = fmaxf(mx, __shfl_xor(mx, 2));
        mx = fmaxf(mx, __shfl_xor(mx, 4));
        mx = fmaxf(mx, __shfl_xor(mx, 8));
        float sum = 0.f;
#pragma unroll
        for (int c = 0; c < 4; ++c) {
          float p = __expf(s[r][c][i] - mx);
          s[r][c][i] = p;
          sum += p;
        }
        sum += __shfl_xor(sum, 1);
        sum += __shfl_xor(sum, 2);
        sum += __shfl_xor(sum, 4);
        sum += __shfl_xor(sum, 8);
        rinv[r][i] = 1.0f / sum;
      }
    }

    // ---- P -> scratch (overlays Q+K; Q/K already consumed into regs)
#pragma unroll
    for (int r = 0; r < 4; ++r)
#pragma unroll
      for (int c = 0; c < 4; ++c)
#pragma unroll
        for (int i = 0; i < 4; ++i) {
          const int row = r * 16 + quad * 4 + i, col = c * 16 + col_l;
          sp[(row * 64 + col) ^ ((row & 7) << 3)] = f2bf(s[r][c][i]);
        }

    // ---- V: C-frag -> PV B-frag purely in registers (cross-quad shuffle)
    s16x8 bv[2][2];
#pragma unroll
    for (int cf = 0; cf < 2; ++cf) {
      const float vb = cf ? vb1 : vb0;
#pragma unroll
      for (int ks = 0; ks < 2; ++ks) {
        const int rA = ks * 2, rB = ks * 2 + 1;
        u32 A0 = pk2(acc[rA][4 + cf][0] + vb, acc[rA][4 + cf][1] + vb);
        u32 A1 = pk2(acc[rA][4 + cf][2] + vb, acc[rA][4 + cf][3] + vb);
        u32 B0 = pk2(acc[rB][4 + cf][0] + vb, acc[rB][4 + cf][1] + vb);
        u32 B1 = pk2(acc[rB][4 + cf][2] + vb, acc[rB][4 + cf][3] + vb);
        const int l0 = ((quad * 2) & 3) * 16 + col_l;
        const int l1 = ((quad * 2 + 1) & 3) * 16 + col_l;
        u32 a0 = (u32)__shfl((int)A0, l0), a1 = (u32)__shfl((int)A1, l0);
        u32 a2 = (u32)__shfl((int)A0, l1), a3 = (u32)__shfl((int)A1, l1);
        u32 b0 = (u32)__shfl((int)B0, l0), b1 = (u32)__shfl((int)B1, l0);
        u32 b2 = (u32)__shfl((int)B0, l1), b3 = (u32)__shfl((int)B1, l1);
        u32x4 wv;
        if (quad < 2) { wv[0] = a0; wv[1] = a1; wv[2] = a2; wv[3] = a3; }
        else          { wv[0] = b0; wv[1] = b1; wv[2] = b2; wv[3] = b3; }
        bv[cf][ks] = __builtin_bit_cast(s16x8, wv);
      }
    }

    // ---- O = P V
    f32x4 o[4][2] = {};
#pragma unroll
    for (int r = 0; r < 4; ++r) {
#pragma unroll
      for (int ks = 0; ks < 2; ++ks) {
        const int row = r * 16 + col_l;
        s16x8 pa = *(const s16x8*)&sp[(row * 64 + ks * 32 + quad * 8) ^ ((row & 7) << 3)];
#pragma unroll
        for (int cf = 0; cf < 2; ++cf)
          o[r][cf] = mfma16(pa, bv[cf][ks], o[r][cf]);
      }
    }

    // ---- normalize, 4x4 shuffle transpose, 8B coalesced-ish stores to AO
#pragma unroll
    for (int r = 0; r < 4; ++r) {
#pragma unroll
      for (int cf = 0; cf < 2; ++cf) {
        float v0 = o[r][cf][0] * rinv[r][0], v1 = o[r][cf][1] * rinv[r][1];
        float v2 = o[r][cf][2] * rinv[r][2], v3 = o[r][cf][3] * rinv[r][3];
        float sA = (lane & 1) ? v0 : v1; sA = __shfl_xor(sA, 1);
        float sB = (lane & 1) ? v2 : v3; sB = __shfl_xor(sB, 1);
        u32 pa_, pb_;
        if (lane & 1) { pa_ = pk2(sA, v1); pb_ = pk2(sB, v3); }
        else          { pa_ = pk2(v0, sA); pb_ = pk2(v2, sB); }
        u32 s2 = (lane & 2) ? pa_ : pb_;
        s2 = (u32)__shfl_xor((int)s2, 2);
        u32x2 val;
        if (lane & 2) { val.x = s2;  val.y = pb_; }
        else          { val.x = pa_; val.y = s2;  }
        const int e = r * 16 + quad * 4 + (col_l & 3);
        const int h = a * 8 + (e >> 3), w = b * 8 + (e & 7);
        const size_t m = (size_t)nimg * 4096 + (size_t)h * 64 + w;
        *(u32x2*)&AO[m * 512 + head * 32 + cf * 16 + (col_l & ~3)] = val;
      }
    }
  }
}

// ---------------- GEMM2: 256x256 tile, BK=64, 8 waves, 8-phase (r3 version) ----------------
__global__ __launch_bounds__(512, 2)
void k_gemm2(const u16* __restrict__ A, const u16* __restrict__ B,
             const float* __restrict__ bias, float* __restrict__ Out) {
  __shared__ u16 lds[65536];
  u16* ldsA = lds;
  u16* ldsB = lds + 32768;
  const int tid = threadIdx.x;
  const int lane = tid & 63, wid = tid >> 6;
  const int quad = lane >> 4, col_l = lane & 15;
  const int wr = wid >> 2, wc = wid & 3;
  const int ntn = 2;

  const int cpx = gridDim.x >> 3;
  const int sb = (blockIdx.x & 7) * cpx + (blockIdx.x >> 3);
  const int mt = sb / ntn, nt = sb - mt * ntn;
  const int m0 = mt * 256, n0 = nt * 256;

  const int srow = tid >> 3;
  const int sch = (tid & 7) ^ (srow & 7);
  const size_t gA = (size_t)(m0 + srow) * 512 + sch * 8;
  const size_t gB = (size_t)(n0 + srow) * 512 + sch * 8;

  auto STAGE = [&](int s) {
    const int bb = s & 1;
    const size_t k = (size_t)s * 64;
#pragma unroll
    for (int g = 0; g < 4; ++g) {
      gload16(A + gA + (size_t)g * 32768 + k, &ldsA[bb * 16384 + g * 4096 + tid * 8]);
      gload16(B + gB + (size_t)g * 32768 + k, &ldsB[bb * 16384 + g * 4096 + tid * 8]);
    }
  };

  STAGE(0);
  STAGE(1);
  asm volatile("s_waitcnt vmcnt(8)" ::: "memory");
  BARRIER();

  const int xsw = (col_l & 7) << 3;
  const int aRB = (wr * 128 + col_l) * 64;
  const int bRB = (wc * 64 + col_l) * 64;

  f32x4 acc[8][4] = {};

  for (int t = 0; t < 8; ++t) {
    const int base = (t & 1) * 16384;
    s16x8 a0[4], a1[4], bfr[4][2];

#pragma unroll
    for (int r = 0; r < 4; ++r)
      a0[r] = *(const s16x8*)&ldsA[base + aRB + r * 1024 + ((quad * 8) ^ xsw)];
#pragma unroll
    for (int c = 0; c < 4; ++c)
      bfr[c][0] = *(const s16x8*)&ldsB[base + bRB + c * 1024 + ((quad * 8) ^ xsw)];
    BARRIER();
    __builtin_amdgcn_s_setprio(1);
#pragma unroll
    for (int r = 0; r < 4; ++r)
#pragma unroll
      for (int c = 0; c < 4; ++c)
        acc[r][c] = mfma16(a0[r], bfr[c][0], acc[r][c]);
    __builtin_amdgcn_s_setprio(0);
    BARRIER();

#pragma unroll
    for (int r = 0; r < 4; ++r)
      a1[r] = *(const s16x8*)&ldsA[base + aRB + r * 1024 + ((32 + quad * 8) ^ xsw)];
#pragma unroll
    for (int c = 0; c < 4; ++c)
      bfr[c][1] = *(const s16x8*)&ldsB[base + bRB + c * 1024 + ((32 + quad * 8) ^ xsw)];
    BARRIER();
    __builtin_amdgcn_s_setprio(1);
#pragma unroll
    for (int r = 0; r < 4; ++r)
#pragma unroll
      for (int c = 0; c < 4; ++c)
        acc[r][c] = mfma16(a1[r], bfr[c][1], acc[r][c]);
    __builtin_amdgcn_s_setprio(0);
    BARRIER();

#pragma unroll
    for (int r = 0; r < 4; ++r)
      a0[r] = *(const s16x8*)&ldsA[base + aRB + (r + 4) * 1024 + ((quad * 8) ^ xsw)];
    BARRIER();
    __builtin_amdgcn_s_setprio(1);
#pragma unroll
    for (int r = 0; r < 4; ++r)
#pragma unroll
      for (int c = 0; c < 4; ++c)
        acc[r + 4][c] = mfma16(a0[r], bfr[c][0], acc[r + 4][c]);
    __builtin_amdgcn_s_setprio(0);
    BARRIER();

#pragma unroll
    for (int r = 0; r < 4; ++r)
      a1[r] = *(const s16x8*)&ldsA[base + aRB + (r + 4) * 1024 + ((32 + quad * 8) ^ xsw)];
    if (t < 6) STAGE(t + 2);
    BARRIER();
    __builtin_amdgcn_s_setprio(1);
#pragma unroll
    for (int r = 0; r < 4; ++r)
#pragma unroll
      for (int c = 0; c < 4; ++c)
        acc[r + 4][c] = mfma16(a1[r], bfr[c][1], acc[r + 4][c]);
    __builtin_amdgcn_s_setprio(0);
    if (t < 6)      asm volatile("s_waitcnt vmcnt(8)" ::: "memory");
    else if (t == 6) asm volatile("s_waitcnt vmcnt(0)" ::: "memory");
    BARRIER();
  }

  // fp32 epilogue: two 128-row passes through LDS
#pragma unroll
  for (int p = 0; p < 2; ++p) {
    if (p) __syncthreads();
#pragma unroll
    for (int c = 0; c < 4; ++c) {
      const float bv = bias[n0 + wc * 64 + c * 16 + col_l];
#pragma unroll
      for (int rr = 0; rr < 4; ++rr) {
        const int r = p * 4 + rr;
        float v0 = acc[r][c][0] + bv, v1 = acc[r][c][1] + bv;
        float v2 = acc[r][c][2] + bv, v3 = acc[r][c][3] + bv;
        float sA = (lane & 1) ? v0 : v1; sA = __shfl_xor(sA, 1);
        float sB = (lane & 1) ? v2 : v3; sB = __shfl_xor(sB, 1);
        float A0, A1, B0, B1;
        if (lane & 1) { A0 = sA; A1 = v1; B0 = sB; B1 = v3; }
        else          { A0 = v0; A1 = sA; B0 = v2; B1 = sB; }
        float t0 = (lane & 2) ? A0 : B0; t0 = __shfl_xor(t0, 2);
        float t1 = (lane & 2) ? A1 : B1; t1 = __shfl_xor(t1, 2);
        f32x4 outv;
        if (lane & 2) { outv[0] = t0; outv[1] = t1; outv[2] = B0; outv[3] = B1; }
        else          { outv[0] = A0; outv[1] = A1; outv[2] = t0; outv[3] = t1; }
        const int lr = wr * 64 + rr * 16 + quad * 4 + (col_l & 3);
        const int ck = (wc * 64 + c * 16 + (col_l & ~3)) >> 2;
        *(f32x4*)((char*)lds + lr * 1024 + ((ck ^ (lr & 7)) << 4)) = outv;
      }
    }
    __syncthreads();
#pragma unroll
    for (int it = 0; it < 16; ++it) {
      const int lr = wid * 16 + it;
      f32x4 v = *(const f32x4*)((char*)lds + lr * 1024 + (((int)lane ^ (lr & 7)) << 4));
      const int m = m0 + (lr >> 6) * 128 + p * 64 + (lr & 63);
      *(f32x4*)&Out[(size_t)m * 512 + n0 + lane * 4] = v;
    }
  }
}

// ---------------- launch ----------------
extern "C" void kernel_launch(void* const* d_in, const int* in_sizes, int n_in,
                              void* d_out, int out_size, void* d_ws, size_t ws_size,
                              hipStream_t stream) {
  const float* x     = (const float*)d_in[0];
  const float* mask  = (const float*)d_in[1];
  const float* qkv_w = (const float*)d_in[2];
  const float* qkv_b = (const float*)d_in[3];
  const float* out_w = (const float*)d_in[4];
  const float* out_b = (const float*)d_in[5];
  const float* btab  = (const float*)d_in[6];

  char* ws = (char*)d_ws;
  u16* xb    = (u16*)ws;                        // 134,217,728 B (x bf16)
  u16* ao    = (u16*)(ws + 134217728);          // 134,217,728 B (attn out bf16)
  u16* wqkvT = (u16*)(ws + 268435456);          // 1,572,864 B
  u16* woT   = (u16*)(ws + 270008320);          // 524,288 B

  k_conv_x<<<65536, 256, 0, stream>>>(x, xb, 16777216);
  k_transpose_w<<<3072, 256, 0, stream>>>(qkv_w, wqkvT, 512, 1536);
  k_transpose_w<<<1024, 256, 0, stream>>>(out_w, woT, 512, 512);
  k_win<<<2048, 512, 0, stream>>>(xb, wqkvT, qkv_b, mask, btab, ao);
  k_gemm2<<<1024, 512, 0, stream>>>(ao, woT, out_b, (float*)d_out);
}

// Round 6
// 1520.964 us; speedup vs baseline: 1.0332x; 1.0332x over previous
//
#include <hip/hip_runtime.h>
#include <hip/hip_bf16.h>
#include <stdint.h>

// Swin windowed MHA: N=32, H=W=64, C=512, heads=16, head_dim=32, window 8x8 (E=64).
// conv x->bf16 ; pack qkv_w into MFMA-fragment order ; transpose out_w ;
// k_winqkv (fused QKV-proj + windowed attention, coalesced packed-W reads, blocked
// AO2 output) ; k_gemm2 (256^2 8-phase, A gathered from AO2).

typedef __attribute__((ext_vector_type(4))) float  f32x4;
typedef __attribute__((ext_vector_type(4))) float  fvec4;
typedef __attribute__((ext_vector_type(8))) short  s16x8;
typedef __attribute__((ext_vector_type(8))) __bf16 bf16x8;
typedef __attribute__((ext_vector_type(2))) unsigned int u32x2;
typedef __attribute__((ext_vector_type(4))) unsigned int u32x4;
typedef unsigned short u16;
typedef unsigned int   u32;
typedef __attribute__((ext_vector_type(4))) u16 u16x4;

__device__ __forceinline__ u16 f2bf(float f) {
  u32 u = __builtin_bit_cast(u32, f);
  u32 r = (u + 0x7FFFu + ((u >> 16) & 1u)) >> 16;
  return (u16)r;
}
__device__ __forceinline__ u32 pk2(float x, float y) {
  return (u32)f2bf(x) | ((u32)f2bf(y) << 16);
}

__device__ __forceinline__ f32x4 mfma16(s16x8 a, s16x8 b, f32x4 c) {
  return __builtin_amdgcn_mfma_f32_16x16x32_bf16((bf16x8)a, (bf16x8)b, c, 0, 0, 0);
}

__device__ __forceinline__ void gload16(const u16* g, u16* l) {
  __builtin_amdgcn_global_load_lds(
      (const __attribute__((address_space(1))) u32*)g,
      (__attribute__((address_space(3))) u32*)l, 16, 0, 0);
}

#define BARRIER() asm volatile("s_barrier" ::: "memory")

// ---------------- conversion / packing kernels ----------------
__global__ void k_conv_x(const float* __restrict__ x, u16* __restrict__ xb, int n4) {
  int i = blockIdx.x * 256 + threadIdx.x;
  if (i >= n4) return;
  fvec4 v = ((const fvec4*)x)[i];
  u16x4 o;
  o.x = f2bf(v.x); o.y = f2bf(v.y); o.z = f2bf(v.z); o.w = f2bf(v.w);
  ((u16x4*)xb)[i] = o;
}

__global__ void k_transpose_w(const float* __restrict__ w, u16* __restrict__ wt, int K, int N) {
  int i = blockIdx.x * 256 + threadIdx.x;
  if (i >= K * N) return;
  int k = i / N, n = i - k * N;
  wt[n * K + k] = f2bf(w[i]);
}

// pack qkv_w [512][1536] f32 -> PW bf16, fragment order:
// PW[(((H*3+s)*2+nf)*16+kt)*64+lane][8] ; frag covers col = s*512+H*32+nf*16+(lane&15),
// k = kt*32+(lane>>4)*8 + 0..7.  98304 chunks of 8 u16.
__global__ void k_pack_wqkv(const float* __restrict__ w, u16* __restrict__ pw) {
  int id = blockIdx.x * 256 + threadIdx.x;
  const int lane = id & 63;
  int r = id >> 6;
  const int kt = r & 15; r >>= 4;
  const int nf = r & 1;  r >>= 1;
  const int s = r % 3;
  const int H = r / 3;
  const int n = s * 512 + H * 32 + nf * 16 + (lane & 15);
  const int k0 = kt * 32 + (lane >> 4) * 8;
  u16 tmp[8];
#pragma unroll
  for (int j = 0; j < 8; ++j) tmp[j] = f2bf(w[(size_t)(k0 + j) * 1536 + n]);
  *(s16x8*)&pw[(size_t)id * 8] = *(const s16x8*)tmp;
}

// ---------------- fused window kernel ----------------
// 1 block = 1 window (2048 blocks), 512 thr = 8 waves, wave w owns heads {2w, 2w+1}.
// LDS: x-window [64][512] bf16 (64KB, chunk-swizzled) + per-wave 8KB scratch.
// Proj B-frags: coalesced loads from packed PW (L2-resident), 2-deep pipeline.
// Output: AO2[win][head][e][d32] bf16, 16B/lane coalesced stores via LDS bounce.
__global__ __launch_bounds__(512, 2)
void k_winqkv(const u16* __restrict__ xb, const u16* __restrict__ PW,
              const float* __restrict__ qkv_b, const float* __restrict__ mask,
              const float* __restrict__ btab, u16* __restrict__ AO2) {
  __shared__ u16 lds[65536];  // 128 KiB
  const int tid = threadIdx.x;
  const int lane = tid & 63, wid = tid >> 6;
  const int quad = lane >> 4, col_l = lane & 15;
  const int win = blockIdx.x;
  const int nimg = win >> 6, a = (win >> 3) & 7, b = win & 7;

  // ---- stage x-window: row = g*8+wid, chunk = lane, src chunk pre-swizzled ^ wid
#pragma unroll
  for (int g = 0; g < 8; ++g) {
    const int h = a * 8 + g, w = b * 8 + wid;
    const size_t m = (size_t)nimg * 4096 + h * 64 + w;
    gload16(xb + m * 512 + ((lane ^ wid) * 8), &lds[(g * 512 + tid) * 8]);
  }
  asm volatile("s_waitcnt vmcnt(0)" ::: "memory");
  BARRIER();

  u16* sq = &lds[32768 + wid * 4096];  // Q [64][32] swizzled
  u16* sk = sq + 2048;                 // K [64][32] swizzled
  u16* sp = sq;                        // P [64][64] swizzled (overlays Q+K)

  const float scale = 0.17677669529663687f;  // 1/sqrt(32)
  const float* mrow = mask + (size_t)(a * 8 + b) * 4096;

#pragma unroll 1
  for (int hh = 0; hh < 2; ++hh) {
    const int head = wid * 2 + hh;
    const float qb0 = qkv_b[head * 32 + col_l],        qb1 = qkv_b[head * 32 + 16 + col_l];
    const float kb0 = qkv_b[512 + head * 32 + col_l],  kb1 = qkv_b[512 + head * 32 + 16 + col_l];
    const float vb0 = qkv_b[1024 + head * 32 + col_l], vb1 = qkv_b[1024 + head * 32 + 16 + col_l];

    // ---- proj: acc[mf][nf], nf = {q0,q1,k0,k1,v0,v1}; B from packed PW (coalesced)
    f32x4 acc[4][6] = {};
    const u16* bp[6];
#pragma unroll
    for (int nf = 0; nf < 6; ++nf)
      bp[nf] = PW + (size_t)(((head * 3 + (nf >> 1)) * 2) + (nf & 1)) * 8192;

#define LOADF(kt, bfv, afv)                                                          \
    {                                                                                \
      _Pragma("unroll")                                                              \
      for (int nf = 0; nf < 6; ++nf)                                                 \
        bfv[nf] = *(const s16x8*)&bp[nf][(kt) * 512 + lane * 8];                     \
      _Pragma("unroll")                                                              \
      for (int mf = 0; mf < 4; ++mf)                                                 \
        afv[mf] = *(const s16x8*)&lds[(mf * 16 + col_l) * 512 +                      \
                                      ((((kt) * 4 + quad) ^ (col_l & 7)) * 8)];      \
    }
#define MFMAF(bfv, afv)                                                              \
    {                                                                                \
      _Pragma("unroll")                                                              \
      for (int mf = 0; mf < 4; ++mf)                                                 \
        _Pragma("unroll")                                                            \
        for (int nf = 0; nf < 6; ++nf)                                               \
          acc[mf][nf] = mfma16(afv[mf], bfv[nf], acc[mf][nf]);                       \
    }

    s16x8 bfA[6], afA[4], bfB[6], afB[4];
    LOADF(0, bfA, afA);
#pragma unroll
    for (int kp = 0; kp < 8; ++kp) {
      LOADF(2 * kp + 1, bfB, afB);
      MFMAF(bfA, afA);
      if (kp < 7) LOADF(2 * kp + 2, bfA, afA);
      MFMAF(bfB, afB);
    }
#undef LOADF
#undef MFMAF

    // ---- write Q (scaled+bias) and K (bias) to scratch: [e][d], chunk ^= (e>>1)&3
#pragma unroll
    for (int r = 0; r < 4; ++r)
#pragma unroll
      for (int half = 0; half < 2; ++half)
#pragma unroll
        for (int i = 0; i < 4; ++i) {
          const int e = r * 16 + quad * 4 + i;
          const int d = half * 16 + col_l;
          const int sw = (((d >> 3) ^ ((e >> 1) & 3)) << 3) + (d & 7);
          sq[e * 32 + sw] = f2bf((acc[r][half][i] + (half ? qb1 : qb0)) * scale);
          sk[e * 32 + sw] = f2bf(acc[r][2 + half][i] + (half ? kb1 : kb0));
        }

    // ---- S = Q K^T
    s16x8 aq[4], bk[4];
    const int ssw = (quad ^ ((col_l >> 1) & 3)) << 3;
#pragma unroll
    for (int t = 0; t < 4; ++t) {
      aq[t] = *(const s16x8*)&sq[(t * 16 + col_l) * 32 + ssw];
      bk[t] = *(const s16x8*)&sk[(t * 16 + col_l) * 32 + ssw];
    }
    f32x4 s[4][4] = {};
#pragma unroll
    for (int r = 0; r < 4; ++r)
#pragma unroll
      for (int c = 0; c < 4; ++c)
        s[r][c] = mfma16(aq[r], bk[c], s[r][c]);

    // ---- bias + mask
#pragma unroll
    for (int r = 0; r < 4; ++r)
#pragma unroll
      for (int c = 0; c < 4; ++c)
#pragma unroll
        for (int i = 0; i < 4; ++i) {
          const int row = r * 16 + quad * 4 + i, col = c * 16 + col_l;
          const int dh = (row >> 3) - (col >> 3) + 7;
          const int dw = (row & 7) - (col & 7) + 7;
          s[r][c][i] += btab[(dh * 15 + dw) * 16 + head] + mrow[row * 64 + col];
        }

    // ---- softmax (deferred 1/sum)
    float rinv[4][4];
#pragma unroll
    for (int r = 0; r < 4; ++r) {
#pragma unroll
      for (int i = 0; i < 4; ++i) {
        float mx = fmaxf(fmaxf(s[r][0][i], s[r][1][i]), fmaxf(s[r][2][i], s[r][3][i]));
        mx = fmaxf(mx, __shfl_xor(mx, 1));
        mx = fmaxf(mx, __shfl_xor(mx, 2));
        mx = fmaxf(mx, __shfl_xor(mx, 4));
        mx = fmaxf(mx, __shfl_xor(mx, 8));
        float sum = 0.f;
#pragma unroll
        for (int c = 0; c < 4; ++c) {
          float p = __expf(s[r][c][i] - mx);
          s[r][c][i] = p;
          sum += p;
        }
        sum += __shfl_xor(sum, 1);
        sum += __shfl_xor(sum, 2);
        sum += __shfl_xor(sum, 4);
        sum += __shfl_xor(sum, 8);
        rinv[r][i] = 1.0f / sum;
      }
    }

    // ---- P -> scratch (overlays Q+K; both already consumed)
#pragma unroll
    for (int r = 0; r < 4; ++r)
#pragma unroll
      for (int c = 0; c < 4; ++c)
#pragma unroll
        for (int i = 0; i < 4; ++i) {
          const int row = r * 16 + quad * 4 + i, col = c * 16 + col_l;
          sp[(row * 64 + col) ^ ((row & 7) << 3)] = f2bf(s[r][c][i]);
        }

    // ---- V: C-frag -> PV B-frag purely in registers (cross-quad shuffle)
    s16x8 bv[2][2];
#pragma unroll
    for (int cf = 0; cf < 2; ++cf) {
      const float vb = cf ? vb1 : vb0;
#pragma unroll
      for (int ks = 0; ks < 2; ++ks) {
        const int rA = ks * 2, rB = ks * 2 + 1;
        u32 A0 = pk2(acc[rA][4 + cf][0] + vb, acc[rA][4 + cf][1] + vb);
        u32 A1 = pk2(acc[rA][4 + cf][2] + vb, acc[rA][4 + cf][3] + vb);
        u32 B0 = pk2(acc[rB][4 + cf][0] + vb, acc[rB][4 + cf][1] + vb);
        u32 B1 = pk2(acc[rB][4 + cf][2] + vb, acc[rB][4 + cf][3] + vb);
        const int l0 = ((quad * 2) & 3) * 16 + col_l;
        const int l1 = ((quad * 2 + 1) & 3) * 16 + col_l;
        u32 a0 = (u32)__shfl((int)A0, l0), a1 = (u32)__shfl((int)A1, l0);
        u32 a2 = (u32)__shfl((int)A0, l1), a3 = (u32)__shfl((int)A1, l1);
        u32 b0 = (u32)__shfl((int)B0, l0), b1 = (u32)__shfl((int)B1, l0);
        u32 b2 = (u32)__shfl((int)B0, l1), b3 = (u32)__shfl((int)B1, l1);
        u32x4 wv;
        if (quad < 2) { wv[0] = a0; wv[1] = a1; wv[2] = a2; wv[3] = a3; }
        else          { wv[0] = b0; wv[1] = b1; wv[2] = b2; wv[3] = b3; }
        bv[cf][ks] = __builtin_bit_cast(s16x8, wv);
      }
    }

    // ---- O = P V
    f32x4 o[4][2] = {};
#pragma unroll
    for (int r = 0; r < 4; ++r) {
#pragma unroll
      for (int ks = 0; ks < 2; ++ks) {
        const int row = r * 16 + col_l;
        s16x8 pa = *(const s16x8*)&sp[(row * 64 + ks * 32 + quad * 8) ^ ((row & 7) << 3)];
#pragma unroll
        for (int cf = 0; cf < 2; ++cf)
          o[r][cf] = mfma16(pa, bv[cf][ks], o[r][cf]);
      }
    }

    // ---- normalize + 4x4 shuffle transpose -> scratch [e][d32] -> 16B coalesced AO2
    u16* so = sp;  // P consumed; reuse first 4KB
#pragma unroll
    for (int r = 0; r < 4; ++r) {
#pragma unroll
      for (int cf = 0; cf < 2; ++cf) {
        float v0 = o[r][cf][0] * rinv[r][0], v1 = o[r][cf][1] * rinv[r][1];
        float v2 = o[r][cf][2] * rinv[r][2], v3 = o[r][cf][3] * rinv[r][3];
        float sA = (lane & 1) ? v0 : v1; sA = __shfl_xor(sA, 1);
        float sB = (lane & 1) ? v2 : v3; sB = __shfl_xor(sB, 1);
        u32 pa_, pb_;
        if (lane & 1) { pa_ = pk2(sA, v1); pb_ = pk2(sB, v3); }
        else          { pa_ = pk2(v0, sA); pb_ = pk2(v2, sB); }
        u32 s2 = (lane & 2) ? pa_ : pb_;
        s2 = (u32)__shfl_xor((int)s2, 2);
        u32x2 val;
        if (lane & 2) { val.x = s2;  val.y = pb_; }
        else          { val.x = pa_; val.y = s2;  }
        const int e = r * 16 + quad * 4 + (col_l & 3);
        *(u32x2*)&so[e * 32 + cf * 16 + (col_l & ~3)] = val;
      }
    }
    const size_t obase = ((size_t)win * 16 + head) * 2048;
#pragma unroll
    for (int it = 0; it < 4; ++it) {
      const int e = it * 16 + (lane >> 2);
      const int dd = (lane & 3) * 8;
      *(s16x8*)&AO2[obase + e * 32 + dd] = *(const s16x8*)&so[e * 32 + dd];
    }
  }
}

// ---------------- GEMM2: 256x256 tile, BK=64, 8 waves, 8-phase; A gathered from AO2 ----------------
__global__ __launch_bounds__(512, 2)
void k_gemm2(const u16* __restrict__ AO2, const u16* __restrict__ B,
             const float* __restrict__ bias, float* __restrict__ Out) {
  __shared__ u16 lds[65536];
  u16* ldsA = lds;
  u16* ldsB = lds + 32768;
  const int tid = threadIdx.x;
  const int lane = tid & 63, wid = tid >> 6;
  const int quad = lane >> 4, col_l = lane & 15;
  const int wr = wid >> 2, wc = wid & 3;
  const int ntn = 2;

  const int cpx = gridDim.x >> 3;
  const int sb = (blockIdx.x & 7) * cpx + (blockIdx.x >> 3);
  const int mt = sb / ntn, nt = sb - mt * ntn;
  const int m0 = mt * 256, n0 = nt * 256;

  const int srow = tid >> 3;
  const int sch = (tid & 7) ^ (srow & 7);
  const size_t gB = (size_t)(n0 + srow) * 512 + sch * 8;

  // A source: AO2[((win*16+head)*64+e)*32+d]; per k-tile s: head = 2s + (sch>>2), d = (sch&3)*8
  size_t baseA[4];
#pragma unroll
  for (int g = 0; g < 4; ++g) {
    const int m = m0 + g * 64 + srow;
    const int nimg = m >> 12, h = (m >> 6) & 63, w = m & 63;
    const int win = nimg * 64 + (h >> 3) * 8 + (w >> 3);
    const int e = (h & 7) * 8 + (w & 7);
    baseA[g] = ((size_t)(win * 16 + (sch >> 2)) * 64 + e) * 32 + (sch & 3) * 8;
  }

  auto STAGE = [&](int s) {
    const int bb = s & 1;
    const size_t k = (size_t)s * 64;
#pragma unroll
    for (int g = 0; g < 4; ++g) {
      gload16(AO2 + baseA[g] + (size_t)s * 4096, &ldsA[bb * 16384 + g * 4096 + tid * 8]);
      gload16(B + gB + (size_t)g * 32768 + k, &ldsB[bb * 16384 + g * 4096 + tid * 8]);
    }
  };

  STAGE(0);
  STAGE(1);
  asm volatile("s_waitcnt vmcnt(8)" ::: "memory");
  BARRIER();

  const int xsw = (col_l & 7) << 3;
  const int aRB = (wr * 128 + col_l) * 64;
  const int bRB = (wc * 64 + col_l) * 64;

  f32x4 acc[8][4] = {};

  for (int t = 0; t < 8; ++t) {
    const int base = (t & 1) * 16384;
    s16x8 a0[4], a1[4], bfr[4][2];

#pragma unroll
    for (int r = 0; r < 4; ++r)
      a0[r] = *(const s16x8*)&ldsA[base + aRB + r * 1024 + ((quad * 8) ^ xsw)];
#pragma unroll
    for (int c = 0; c < 4; ++c)
      bfr[c][0] = *(const s16x8*)&ldsB[base + bRB + c * 1024 + ((quad * 8) ^ xsw)];
    BARRIER();
    __builtin_amdgcn_s_setprio(1);
#pragma unroll
    for (int r = 0; r < 4; ++r)
#pragma unroll
      for (int c = 0; c < 4; ++c)
        acc[r][c] = mfma16(a0[r], bfr[c][0], acc[r][c]);
    __builtin_amdgcn_s_setprio(0);
    BARRIER();

#pragma unroll
    for (int r = 0; r < 4; ++r)
      a1[r] = *(const s16x8*)&ldsA[base + aRB + r * 1024 + ((32 + quad * 8) ^ xsw)];
#pragma unroll
    for (int c = 0; c < 4; ++c)
      bfr[c][1] = *(const s16x8*)&ldsB[base + bRB + c * 1024 + ((32 + quad * 8) ^ xsw)];
    BARRIER();
    __builtin_amdgcn_s_setprio(1);
#pragma unroll
    for (int r = 0; r < 4; ++r)
#pragma unroll
      for (int c = 0; c < 4; ++c)
        acc[r][c] = mfma16(a1[r], bfr[c][1], acc[r][c]);
    __builtin_amdgcn_s_setprio(0);
    BARRIER();

#pragma unroll
    for (int r = 0; r < 4; ++r)
      a0[r] = *(const s16x8*)&ldsA[base + aRB + (r + 4) * 1024 + ((quad * 8) ^ xsw)];
    BARRIER();
    __builtin_amdgcn_s_setprio(1);
#pragma unroll
    for (int r = 0; r < 4; ++r)
#pragma unroll
      for (int c = 0; c < 4; ++c)
        acc[r + 4][c] = mfma16(a0[r], bfr[c][0], acc[r + 4][c]);
    __builtin_amdgcn_s_setprio(0);
    BARRIER();

#pragma unroll
    for (int r = 0; r < 4; ++r)
      a1[r] = *(const s16x8*)&ldsA[base + aRB + (r + 4) * 1024 + ((32 + quad * 8) ^ xsw)];
    if (t < 6) STAGE(t + 2);
    BARRIER();
    __builtin_amdgcn_s_setprio(1);
#pragma unroll
    for (int r = 0; r < 4; ++r)
#pragma unroll
      for (int c = 0; c < 4; ++c)
        acc[r + 4][c] = mfma16(a1[r], bfr[c][1], acc[r + 4][c]);
    __builtin_amdgcn_s_setprio(0);
    if (t < 6)       asm volatile("s_waitcnt vmcnt(8)" ::: "memory");
    else if (t == 6) asm volatile("s_waitcnt vmcnt(0)" ::: "memory");
    BARRIER();
  }

  // fp32 epilogue: two 128-row passes through LDS
#pragma unroll
  for (int p = 0; p < 2; ++p) {
    if (p) __syncthreads();
#pragma unroll
    for (int c = 0; c < 4; ++c) {
      const float bv = bias[n0 + wc * 64 + c * 16 + col_l];
#pragma unroll
      for (int rr = 0; rr < 4; ++rr) {
        const int r = p * 4 + rr;
        float v0 = acc[r][c][0] + bv, v1 = acc[r][c][1] + bv;
        float v2 = acc[r][c][2] + bv, v3 = acc[r][c][3] + bv;
        float sA = (lane & 1) ? v0 : v1; sA = __shfl_xor(sA, 1);
        float sB = (lane & 1) ? v2 : v3; sB = __shfl_xor(sB, 1);
        float A0, A1, B0, B1;
        if (lane & 1) { A0 = sA; A1 = v1; B0 = sB; B1 = v3; }
        else          { A0 = v0; A1 = sA; B0 = v2; B1 = sB; }
        float t0 = (lane & 2) ? A0 : B0; t0 = __shfl_xor(t0, 2);
        float t1 = (lane & 2) ? A1 : B1; t1 = __shfl_xor(t1, 2);
        f32x4 outv;
        if (lane & 2) { outv[0] = t0; outv[1] = t1; outv[2] = B0; outv[3] = B1; }
        else          { outv[0] = A0; outv[1] = A1; outv[2] = t0; outv[3] = t1; }
        const int lr = wr * 64 + rr * 16 + quad * 4 + (col_l & 3);
        const int ck = (wc * 64 + c * 16 + (col_l & ~3)) >> 2;
        *(f32x4*)((char*)lds + lr * 1024 + ((ck ^ (lr & 7)) << 4)) = outv;
      }
    }
    __syncthreads();
#pragma unroll
    for (int it = 0; it < 16; ++it) {
      const int lr = wid * 16 + it;
      f32x4 v = *(const f32x4*)((char*)lds + lr * 1024 + (((int)lane ^ (lr & 7)) << 4));
      const int m = m0 + (lr >> 6) * 128 + p * 64 + (lr & 63);
      *(f32x4*)&Out[(size_t)m * 512 + n0 + lane * 4] = v;
    }
  }
}

// ---------------- launch ----------------
extern "C" void kernel_launch(void* const* d_in, const int* in_sizes, int n_in,
                              void* d_out, int out_size, void* d_ws, size_t ws_size,
                              hipStream_t stream) {
  const float* x     = (const float*)d_in[0];
  const float* mask  = (const float*)d_in[1];
  const float* qkv_w = (const float*)d_in[2];
  const float* qkv_b = (const float*)d_in[3];
  const float* out_w = (const float*)d_in[4];
  const float* out_b = (const float*)d_in[5];
  const float* btab  = (const float*)d_in[6];

  char* ws = (char*)d_ws;
  u16* xb  = (u16*)ws;                          // 134,217,728 B (x bf16)
  u16* ao2 = (u16*)(ws + 134217728);            // 134,217,728 B (attn out, blocked)
  u16* pw  = (u16*)(ws + 268435456);            // 1,572,864 B (packed qkv_w)
  u16* woT = (u16*)(ws + 270008320);            // 524,288 B

  k_conv_x<<<65536, 256, 0, stream>>>(x, xb, 16777216);
  k_pack_wqkv<<<384, 256, 0, stream>>>(qkv_w, pw);
  k_transpose_w<<<1024, 256, 0, stream>>>(out_w, woT, 512, 512);
  k_winqkv<<<2048, 512, 0, stream>>>(xb, pw, qkv_b, mask, btab, ao2);
  k_gemm2<<<1024, 512, 0, stream>>>(ao2, woT, out_b, (float*)d_out);
}

// Round 7
// 1375.652 us; speedup vs baseline: 1.1423x; 1.1056x over previous
//
#include <hip/hip_runtime.h>
#include <hip/hip_bf16.h>
#include <stdint.h>

// Swin windowed MHA: N=32, H=W=64, C=512, heads=16, head_dim=32, window 8x8 (E=64).
// conv x->bf16 ; pack qkv_w into MFMA-fragment order ; transpose out_w ;
// k_winqkv (fused QKV-proj + windowed attention; launch_bounds(512,1) so no spills) ;
// k_gemm2 (256^2 8-phase, A gathered from AO2).

typedef __attribute__((ext_vector_type(4))) float  f32x4;
typedef __attribute__((ext_vector_type(4))) float  fvec4;
typedef __attribute__((ext_vector_type(8))) short  s16x8;
typedef __attribute__((ext_vector_type(8))) __bf16 bf16x8;
typedef __attribute__((ext_vector_type(2))) unsigned int u32x2;
typedef __attribute__((ext_vector_type(4))) unsigned int u32x4;
typedef unsigned short u16;
typedef unsigned int   u32;
typedef __attribute__((ext_vector_type(4))) u16 u16x4;

__device__ __forceinline__ u16 f2bf(float f) {
  u32 u = __builtin_bit_cast(u32, f);
  u32 r = (u + 0x7FFFu + ((u >> 16) & 1u)) >> 16;
  return (u16)r;
}
__device__ __forceinline__ u32 pk2(float x, float y) {
  return (u32)f2bf(x) | ((u32)f2bf(y) << 16);
}

__device__ __forceinline__ f32x4 mfma16(s16x8 a, s16x8 b, f32x4 c) {
  return __builtin_amdgcn_mfma_f32_16x16x32_bf16((bf16x8)a, (bf16x8)b, c, 0, 0, 0);
}

__device__ __forceinline__ void gload16(const u16* g, u16* l) {
  __builtin_amdgcn_global_load_lds(
      (const __attribute__((address_space(1))) u32*)g,
      (__attribute__((address_space(3))) u32*)l, 16, 0, 0);
}

#define BARRIER() asm volatile("s_barrier" ::: "memory")

// ---------------- conversion / packing kernels ----------------
__global__ void k_conv_x(const float* __restrict__ x, u16* __restrict__ xb, int n4) {
  int i = blockIdx.x * 256 + threadIdx.x;
  if (i >= n4) return;
  fvec4 v = ((const fvec4*)x)[i];
  u16x4 o;
  o.x = f2bf(v.x); o.y = f2bf(v.y); o.z = f2bf(v.z); o.w = f2bf(v.w);
  ((u16x4*)xb)[i] = o;
}

__global__ void k_transpose_w(const float* __restrict__ w, u16* __restrict__ wt, int K, int N) {
  int i = blockIdx.x * 256 + threadIdx.x;
  if (i >= K * N) return;
  int k = i / N, n = i - k * N;
  wt[n * K + k] = f2bf(w[i]);
}

// pack qkv_w [512][1536] f32 -> PW bf16 fragment order:
// PW[(((H*3+s)*2+nf)*16+kt)*64+lane][8]; col = s*512+H*32+nf*16+(lane&15),
// k = kt*32+(lane>>4)*8 + 0..7
__global__ void k_pack_wqkv(const float* __restrict__ w, u16* __restrict__ pw) {
  int id = blockIdx.x * 256 + threadIdx.x;
  const int lane = id & 63;
  int r = id >> 6;
  const int kt = r & 15; r >>= 4;
  const int nf = r & 1;  r >>= 1;
  const int s = r % 3;
  const int H = r / 3;
  const int n = s * 512 + H * 32 + nf * 16 + (lane & 15);
  const int k0 = kt * 32 + (lane >> 4) * 8;
  u16 tmp[8];
#pragma unroll
  for (int j = 0; j < 8; ++j) tmp[j] = f2bf(w[(size_t)(k0 + j) * 1536 + n]);
  *(s16x8*)&pw[(size_t)id * 8] = *(const s16x8*)tmp;
}

// ---------------- fused window kernel ----------------
// 1 block = 1 window (2048 blocks), 512 thr = 8 waves, wave w owns heads {2w, 2w+1}.
// LDS: x-window [64][512] bf16 (64KB, chunk-swizzled) + per-wave 8KB scratch.
// launch_bounds(512,1): LDS already limits to 1 block/CU; 256-VGPR budget avoids spills.
__global__ __launch_bounds__(512, 1)
void k_winqkv(const u16* __restrict__ xb, const u16* __restrict__ PW,
              const float* __restrict__ qkv_b, const float* __restrict__ mask,
              const float* __restrict__ btab, u16* __restrict__ AO2) {
  __shared__ u16 lds[65536];  // 128 KiB
  const int tid = threadIdx.x;
  const int lane = tid & 63, wid = tid >> 6;
  const int quad = lane >> 4, col_l = lane & 15;
  const int win = blockIdx.x;
  const int nimg = win >> 6, a = (win >> 3) & 7, b = win & 7;

  // ---- stage x-window: row = g*8+wid, chunk = lane, src chunk pre-swizzled ^ wid
#pragma unroll
  for (int g = 0; g < 8; ++g) {
    const int h = a * 8 + g, w = b * 8 + wid;
    const size_t m = (size_t)nimg * 4096 + h * 64 + w;
    gload16(xb + m * 512 + ((lane ^ wid) * 8), &lds[(g * 512 + tid) * 8]);
  }
  asm volatile("s_waitcnt vmcnt(0)" ::: "memory");
  BARRIER();

  u16* sq = &lds[32768 + wid * 4096];  // Q [64][32] swizzled
  u16* sk = sq + 2048;                 // K [64][32] swizzled
  u16* sp = sq;                        // P [64][64] swizzled (overlays Q+K)

  const float scale = 0.17677669529663687f;  // 1/sqrt(32)
  const float* mrow = mask + (size_t)(a * 8 + b) * 4096;

#pragma unroll 1
  for (int hh = 0; hh < 2; ++hh) {
    const int head = wid * 2 + hh;
    const float qb0 = qkv_b[head * 32 + col_l],        qb1 = qkv_b[head * 32 + 16 + col_l];
    const float kb0 = qkv_b[512 + head * 32 + col_l],  kb1 = qkv_b[512 + head * 32 + 16 + col_l];
    const float vb0 = qkv_b[1024 + head * 32 + col_l], vb1 = qkv_b[1024 + head * 32 + 16 + col_l];

    // ---- proj: acc[mf][nf], nf = {q0,q1,k0,k1,v0,v1}; B from packed PW (coalesced),
    // single-buffered frags (low reg pressure; compiler schedules ahead within 256)
    f32x4 acc[4][6] = {};
    const u16* bp[6];
#pragma unroll
    for (int nf = 0; nf < 6; ++nf)
      bp[nf] = PW + (size_t)(((head * 3 + (nf >> 1)) * 2) + (nf & 1)) * 8192;

#pragma unroll 1
    for (int kt = 0; kt < 16; ++kt) {
      s16x8 bf[6], af[4];
#pragma unroll
      for (int nf = 0; nf < 6; ++nf)
        bf[nf] = *(const s16x8*)&bp[nf][kt * 512 + lane * 8];
#pragma unroll
      for (int mf = 0; mf < 4; ++mf)
        af[mf] = *(const s16x8*)&lds[(mf * 16 + col_l) * 512 +
                                     (((kt * 4 + quad) ^ (col_l & 7)) * 8)];
#pragma unroll
      for (int mf = 0; mf < 4; ++mf)
#pragma unroll
        for (int nf = 0; nf < 6; ++nf)
          acc[mf][nf] = mfma16(af[mf], bf[nf], acc[mf][nf]);
    }

    // ---- write Q (scaled+bias) and K (bias) to scratch: [e][d], chunk ^= (e>>1)&3
#pragma unroll
    for (int r = 0; r < 4; ++r)
#pragma unroll
      for (int half = 0; half < 2; ++half)
#pragma unroll
        for (int i = 0; i < 4; ++i) {
          const int e = r * 16 + quad * 4 + i;
          const int d = half * 16 + col_l;
          const int sw = (((d >> 3) ^ ((e >> 1) & 3)) << 3) + (d & 7);
          sq[e * 32 + sw] = f2bf((acc[r][half][i] + (half ? qb1 : qb0)) * scale);
          sk[e * 32 + sw] = f2bf(acc[r][2 + half][i] + (half ? kb1 : kb0));
        }

    // ---- S = Q K^T
    s16x8 aq[4], bk[4];
    const int ssw = (quad ^ ((col_l >> 1) & 3)) << 3;
#pragma unroll
    for (int t = 0; t < 4; ++t) {
      aq[t] = *(const s16x8*)&sq[(t * 16 + col_l) * 32 + ssw];
      bk[t] = *(const s16x8*)&sk[(t * 16 + col_l) * 32 + ssw];
    }
    f32x4 s[4][4] = {};
#pragma unroll
    for (int r = 0; r < 4; ++r)
#pragma unroll
      for (int c = 0; c < 4; ++c)
        s[r][c] = mfma16(aq[r], bk[c], s[r][c]);

    // ---- bias + mask
#pragma unroll
    for (int r = 0; r < 4; ++r)
#pragma unroll
      for (int c = 0; c < 4; ++c)
#pragma unroll
        for (int i = 0; i < 4; ++i) {
          const int row = r * 16 + quad * 4 + i, col = c * 16 + col_l;
          const int dh = (row >> 3) - (col >> 3) + 7;
          const int dw = (row & 7) - (col & 7) + 7;
          s[r][c][i] += btab[(dh * 15 + dw) * 16 + head] + mrow[row * 64 + col];
        }

    // ---- softmax (deferred 1/sum)
    float rinv[4][4];
#pragma unroll
    for (int r = 0; r < 4; ++r) {
#pragma unroll
      for (int i = 0; i < 4; ++i) {
        float mx = fmaxf(fmaxf(s[r][0][i], s[r][1][i]), fmaxf(s[r][2][i], s[r][3][i]));
        mx = fmaxf(mx, __shfl_xor(mx, 1));
        mx = fmaxf(mx, __shfl_xor(mx, 2));
        mx = fmaxf(mx, __shfl_xor(mx, 4));
        mx = fmaxf(mx, __shfl_xor(mx, 8));
        float sum = 0.f;
#pragma unroll
        for (int c = 0; c < 4; ++c) {
          float p = __expf(s[r][c][i] - mx);
          s[r][c][i] = p;
          sum += p;
        }
        sum += __shfl_xor(sum, 1);
        sum += __shfl_xor(sum, 2);
        sum += __shfl_xor(sum, 4);
        sum += __shfl_xor(sum, 8);
        rinv[r][i] = 1.0f / sum;
      }
    }

    // ---- P -> scratch (overlays Q+K; both already consumed)
#pragma unroll
    for (int r = 0; r < 4; ++r)
#pragma unroll
      for (int c = 0; c < 4; ++c)
#pragma unroll
        for (int i = 0; i < 4; ++i) {
          const int row = r * 16 + quad * 4 + i, col = c * 16 + col_l;
          sp[(row * 64 + col) ^ ((row & 7) << 3)] = f2bf(s[r][c][i]);
        }

    // ---- V: C-frag -> PV B-frag purely in registers (cross-quad shuffle)
    s16x8 bv[2][2];
#pragma unroll
    for (int cf = 0; cf < 2; ++cf) {
      const float vb = cf ? vb1 : vb0;
#pragma unroll
      for (int ks = 0; ks < 2; ++ks) {
        const int rA = ks * 2, rB = ks * 2 + 1;
        u32 A0 = pk2(acc[rA][4 + cf][0] + vb, acc[rA][4 + cf][1] + vb);
        u32 A1 = pk2(acc[rA][4 + cf][2] + vb, acc[rA][4 + cf][3] + vb);
        u32 B0 = pk2(acc[rB][4 + cf][0] + vb, acc[rB][4 + cf][1] + vb);
        u32 B1 = pk2(acc[rB][4 + cf][2] + vb, acc[rB][4 + cf][3] + vb);
        const int l0 = ((quad * 2) & 3) * 16 + col_l;
        const int l1 = ((quad * 2 + 1) & 3) * 16 + col_l;
        u32 a0 = (u32)__shfl((int)A0, l0), a1 = (u32)__shfl((int)A1, l0);
        u32 a2 = (u32)__shfl((int)A0, l1), a3 = (u32)__shfl((int)A1, l1);
        u32 b0 = (u32)__shfl((int)B0, l0), b1 = (u32)__shfl((int)B1, l0);
        u32 b2 = (u32)__shfl((int)B0, l1), b3 = (u32)__shfl((int)B1, l1);
        u32x4 wv;
        if (quad < 2) { wv[0] = a0; wv[1] = a1; wv[2] = a2; wv[3] = a3; }
        else          { wv[0] = b0; wv[1] = b1; wv[2] = b2; wv[3] = b3; }
        bv[cf][ks] = __builtin_bit_cast(s16x8, wv);
      }
    }

    // ---- O = P V
    f32x4 o[4][2] = {};
#pragma unroll
    for (int r = 0; r < 4; ++r) {
#pragma unroll
      for (int ks = 0; ks < 2; ++ks) {
        const int row = r * 16 + col_l;
        s16x8 pa = *(const s16x8*)&sp[(row * 64 + ks * 32 + quad * 8) ^ ((row & 7) << 3)];
#pragma unroll
        for (int cf = 0; cf < 2; ++cf)
          o[r][cf] = mfma16(pa, bv[cf][ks], o[r][cf]);
      }
    }

    // ---- normalize + 4x4 shuffle transpose -> scratch [e][d32] -> 16B coalesced AO2
    u16* so = sp;  // P consumed; reuse first 4KB
#pragma unroll
    for (int r = 0; r < 4; ++r) {
#pragma unroll
      for (int cf = 0; cf < 2; ++cf) {
        float v0 = o[r][cf][0] * rinv[r][0], v1 = o[r][cf][1] * rinv[r][1];
        float v2 = o[r][cf][2] * rinv[r][2], v3 = o[r][cf][3] * rinv[r][3];
        float sA = (lane & 1) ? v0 : v1; sA = __shfl_xor(sA, 1);
        float sB = (lane & 1) ? v2 : v3; sB = __shfl_xor(sB, 1);
        u32 pa_, pb_;
        if (lane & 1) { pa_ = pk2(sA, v1); pb_ = pk2(sB, v3); }
        else          { pa_ = pk2(v0, sA); pb_ = pk2(v2, sB); }
        u32 s2 = (lane & 2) ? pa_ : pb_;
        s2 = (u32)__shfl_xor((int)s2, 2);
        u32x2 val;
        if (lane & 2) { val.x = s2;  val.y = pb_; }
        else          { val.x = pa_; val.y = s2;  }
        const int e = r * 16 + quad * 4 + (col_l & 3);
        *(u32x2*)&so[e * 32 + cf * 16 + (col_l & ~3)] = val;
      }
    }
    const size_t obase = ((size_t)win * 16 + head) * 2048;
#pragma unroll
    for (int it = 0; it < 4; ++it) {
      const int e = it * 16 + (lane >> 2);
      const int dd = (lane & 3) * 8;
      *(s16x8*)&AO2[obase + e * 32 + dd] = *(const s16x8*)&so[e * 32 + dd];
    }
  }
}

// ---------------- GEMM2: 256x256 tile, BK=64, 8 waves, 8-phase; A gathered from AO2 ----------------
__global__ __launch_bounds__(512, 2)
void k_gemm2(const u16* __restrict__ AO2, const u16* __restrict__ B,
             const float* __restrict__ bias, float* __restrict__ Out) {
  __shared__ u16 lds[65536];
  u16* ldsA = lds;
  u16* ldsB = lds + 32768;
  const int tid = threadIdx.x;
  const int lane = tid & 63, wid = tid >> 6;
  const int quad = lane >> 4, col_l = lane & 15;
  const int wr = wid >> 2, wc = wid & 3;
  const int ntn = 2;

  const int cpx = gridDim.x >> 3;
  const int sb = (blockIdx.x & 7) * cpx + (blockIdx.x >> 3);
  const int mt = sb / ntn, nt = sb - mt * ntn;
  const int m0 = mt * 256, n0 = nt * 256;

  const int srow = tid >> 3;
  const int sch = (tid & 7) ^ (srow & 7);
  const size_t gB = (size_t)(n0 + srow) * 512 + sch * 8;

  size_t baseA[4];
#pragma unroll
  for (int g = 0; g < 4; ++g) {
    const int m = m0 + g * 64 + srow;
    const int nimg = m >> 12, h = (m >> 6) & 63, w = m & 63;
    const int win = nimg * 64 + (h >> 3) * 8 + (w >> 3);
    const int e = (h & 7) * 8 + (w & 7);
    baseA[g] = ((size_t)(win * 16 + (sch >> 2)) * 64 + e) * 32 + (sch & 3) * 8;
  }

  auto STAGE = [&](int s) {
    const int bb = s & 1;
    const size_t k = (size_t)s * 64;
#pragma unroll
    for (int g = 0; g < 4; ++g) {
      gload16(AO2 + baseA[g] + (size_t)s * 4096, &ldsA[bb * 16384 + g * 4096 + tid * 8]);
      gload16(B + gB + (size_t)g * 32768 + k, &ldsB[bb * 16384 + g * 4096 + tid * 8]);
    }
  };

  STAGE(0);
  STAGE(1);
  asm volatile("s_waitcnt vmcnt(8)" ::: "memory");
  BARRIER();

  const int xsw = (col_l & 7) << 3;
  const int aRB = (wr * 128 + col_l) * 64;
  const int bRB = (wc * 64 + col_l) * 64;

  f32x4 acc[8][4] = {};

  for (int t = 0; t < 8; ++t) {
    const int base = (t & 1) * 16384;
    s16x8 a0[4], a1[4], bfr[4][2];

#pragma unroll
    for (int r = 0; r < 4; ++r)
      a0[r] = *(const s16x8*)&ldsA[base + aRB + r * 1024 + ((quad * 8) ^ xsw)];
#pragma unroll
    for (int c = 0; c < 4; ++c)
      bfr[c][0] = *(const s16x8*)&ldsB[base + bRB + c * 1024 + ((quad * 8) ^ xsw)];
    BARRIER();
    __builtin_amdgcn_s_setprio(1);
#pragma unroll
    for (int r = 0; r < 4; ++r)
#pragma unroll
      for (int c = 0; c < 4; ++c)
        acc[r][c] = mfma16(a0[r], bfr[c][0], acc[r][c]);
    __builtin_amdgcn_s_setprio(0);
    BARRIER();

#pragma unroll
    for (int r = 0; r < 4; ++r)
      a1[r] = *(const s16x8*)&ldsA[base + aRB + r * 1024 + ((32 + quad * 8) ^ xsw)];
#pragma unroll
    for (int c = 0; c < 4; ++c)
      bfr[c][1] = *(const s16x8*)&ldsB[base + bRB + c * 1024 + ((32 + quad * 8) ^ xsw)];
    BARRIER();
    __builtin_amdgcn_s_setprio(1);
#pragma unroll
    for (int r = 0; r < 4; ++r)
#pragma unroll
      for (int c = 0; c < 4; ++c)
        acc[r][c] = mfma16(a1[r], bfr[c][1], acc[r][c]);
    __builtin_amdgcn_s_setprio(0);
    BARRIER();

#pragma unroll
    for (int r = 0; r < 4; ++r)
      a0[r] = *(const s16x8*)&ldsA[base + aRB + (r + 4) * 1024 + ((quad * 8) ^ xsw)];
    BARRIER();
    __builtin_amdgcn_s_setprio(1);
#pragma unroll
    for (int r = 0; r < 4; ++r)
#pragma unroll
      for (int c = 0; c < 4; ++c)
        acc[r + 4][c] = mfma16(a0[r], bfr[c][0], acc[r + 4][c]);
    __builtin_amdgcn_s_setprio(0);
    BARRIER();

#pragma unroll
    for (int r = 0; r < 4; ++r)
      a1[r] = *(const s16x8*)&ldsA[base + aRB + (r + 4) * 1024 + ((32 + quad * 8) ^ xsw)];
    if (t < 6) STAGE(t + 2);
    BARRIER();
    __builtin_amdgcn_s_setprio(1);
#pragma unroll
    for (int r = 0; r < 4; ++r)
#pragma unroll
      for (int c = 0; c < 4; ++c)
        acc[r + 4][c] = mfma16(a1[r], bfr[c][1], acc[r + 4][c]);
    __builtin_amdgcn_s_setprio(0);
    if (t < 6)       asm volatile("s_waitcnt vmcnt(8)" ::: "memory");
    else if (t == 6) asm volatile("s_waitcnt vmcnt(0)" ::: "memory");
    BARRIER();
  }

  // fp32 epilogue: two 128-row passes through LDS
#pragma unroll
  for (int p = 0; p < 2; ++p) {
    if (p) __syncthreads();
#pragma unroll
    for (int c = 0; c < 4; ++c) {
      const float bv = bias[n0 + wc * 64 + c * 16 + col_l];
#pragma unroll
      for (int rr = 0; rr < 4; ++rr) {
        const int r = p * 4 + rr;
        float v0 = acc[r][c][0] + bv, v1 = acc[r][c][1] + bv;
        float v2 = acc[r][c][2] + bv, v3 = acc[r][c][3] + bv;
        float sA = (lane & 1) ? v0 : v1; sA = __shfl_xor(sA, 1);
        float sB = (lane & 1) ? v2 : v3; sB = __shfl_xor(sB, 1);
        float A0, A1, B0, B1;
        if (lane & 1) { A0 = sA; A1 = v1; B0 = sB; B1 = v3; }
        else          { A0 = v0; A1 = sA; B0 = v2; B1 = sB; }
        float t0 = (lane & 2) ? A0 : B0; t0 = __shfl_xor(t0, 2);
        float t1 = (lane & 2) ? A1 : B1; t1 = __shfl_xor(t1, 2);
        f32x4 outv;
        if (lane & 2) { outv[0] = t0; outv[1] = t1; outv[2] = B0; outv[3] = B1; }
        else          { outv[0] = A0; outv[1] = A1; outv[2] = t0; outv[3] = t1; }
        const int lr = wr * 64 + rr * 16 + quad * 4 + (col_l & 3);
        const int ck = (wc * 64 + c * 16 + (col_l & ~3)) >> 2;
        *(f32x4*)((char*)lds + lr * 1024 + ((ck ^ (lr & 7)) << 4)) = outv;
      }
    }
    __syncthreads();
#pragma unroll
    for (int it = 0; it < 16; ++it) {
      const int lr = wid * 16 + it;
      f32x4 v = *(const f32x4*)((char*)lds + lr * 1024 + (((int)lane ^ (lr & 7)) << 4));
      const int m = m0 + (lr >> 6) * 128 + p * 64 + (lr & 63);
      *(f32x4*)&Out[(size_t)m * 512 + n0 + lane * 4] = v;
    }
  }
}

// ---------------- launch ----------------
extern "C" void kernel_launch(void* const* d_in, const int* in_sizes, int n_in,
                              void* d_out, int out_size, void* d_ws, size_t ws_size,
                              hipStream_t stream) {
  const float* x     = (const float*)d_in[0];
  const float* mask  = (const float*)d_in[1];
  const float* qkv_w = (const float*)d_in[2];
  const float* qkv_b = (const float*)d_in[3];
  const float* out_w = (const float*)d_in[4];
  const float* out_b = (const float*)d_in[5];
  const float* btab  = (const float*)d_in[6];

  char* ws = (char*)d_ws;
  u16* xb  = (u16*)ws;                          // 134,217,728 B (x bf16)
  u16* ao2 = (u16*)(ws + 134217728);            // 134,217,728 B (attn out, blocked)
  u16* pw  = (u16*)(ws + 268435456);            // 1,572,864 B (packed qkv_w)
  u16* woT = (u16*)(ws + 270008320);            // 524,288 B

  k_conv_x<<<65536, 256, 0, stream>>>(x, xb, 16777216);
  k_pack_wqkv<<<384, 256, 0, stream>>>(qkv_w, pw);
  k_transpose_w<<<1024, 256, 0, stream>>>(out_w, woT, 512, 512);
  k_winqkv<<<2048, 512, 0, stream>>>(xb, pw, qkv_b, mask, btab, ao2);
  k_gemm2<<<1024, 512, 0, stream>>>(ao2, woT, out_b, (float*)d_out);
}

// Round 8
// 1328.361 us; speedup vs baseline: 1.1830x; 1.0356x over previous
//
#include <hip/hip_runtime.h>
#include <hip/hip_bf16.h>
#include <stdint.h>

// Swin windowed MHA: N=32, H=W=64, C=512, heads=16, head_dim=32, window 8x8 (E=64).
// conv x->bf16 ; pack qkv_w (fragment order) ; transpose out_w ;
// k_winqkv (fused QKV-proj + windowed attention, TWO-PASS proj to fit 128 VGPRs) ;
// k_gemm2 (256^2 8-phase, A gathered from AO2).

typedef __attribute__((ext_vector_type(4))) float  f32x4;
typedef __attribute__((ext_vector_type(4))) float  fvec4;
typedef __attribute__((ext_vector_type(8))) short  s16x8;
typedef __attribute__((ext_vector_type(8))) __bf16 bf16x8;
typedef __attribute__((ext_vector_type(2))) unsigned int u32x2;
typedef __attribute__((ext_vector_type(4))) unsigned int u32x4;
typedef unsigned short u16;
typedef unsigned int   u32;
typedef __attribute__((ext_vector_type(4))) u16 u16x4;

__device__ __forceinline__ u16 f2bf(float f) {
  u32 u = __builtin_bit_cast(u32, f);
  u32 r = (u + 0x7FFFu + ((u >> 16) & 1u)) >> 16;
  return (u16)r;
}
__device__ __forceinline__ u32 pk2(float x, float y) {
  return (u32)f2bf(x) | ((u32)f2bf(y) << 16);
}

__device__ __forceinline__ f32x4 mfma16(s16x8 a, s16x8 b, f32x4 c) {
  return __builtin_amdgcn_mfma_f32_16x16x32_bf16((bf16x8)a, (bf16x8)b, c, 0, 0, 0);
}

__device__ __forceinline__ void gload16(const u16* g, u16* l) {
  __builtin_amdgcn_global_load_lds(
      (const __attribute__((address_space(1))) u32*)g,
      (__attribute__((address_space(3))) u32*)l, 16, 0, 0);
}

#define BARRIER() asm volatile("s_barrier" ::: "memory")

// ---------------- conversion / packing kernels ----------------
__global__ void k_conv_x(const float* __restrict__ x, u16* __restrict__ xb, int n4) {
  int i = blockIdx.x * 256 + threadIdx.x;
  if (i >= n4) return;
  fvec4 v = ((const fvec4*)x)[i];
  u16x4 o;
  o.x = f2bf(v.x); o.y = f2bf(v.y); o.z = f2bf(v.z); o.w = f2bf(v.w);
  ((u16x4*)xb)[i] = o;
}

__global__ void k_transpose_w(const float* __restrict__ w, u16* __restrict__ wt, int K, int N) {
  int i = blockIdx.x * 256 + threadIdx.x;
  if (i >= K * N) return;
  int k = i / N, n = i - k * N;
  wt[n * K + k] = f2bf(w[i]);
}

// pack qkv_w [512][1536] f32 -> PW bf16 fragment order:
// PW[(((H*3+s)*2+nf)*16+kt)*64+lane][8]; col = s*512+H*32+nf*16+(lane&15),
// k = kt*32+(lane>>4)*8 + 0..7
__global__ void k_pack_wqkv(const float* __restrict__ w, u16* __restrict__ pw) {
  int id = blockIdx.x * 256 + threadIdx.x;
  const int lane = id & 63;
  int r = id >> 6;
  const int kt = r & 15; r >>= 4;
  const int nf = r & 1;  r >>= 1;
  const int s = r % 3;
  const int H = r / 3;
  const int n = s * 512 + H * 32 + nf * 16 + (lane & 15);
  const int k0 = kt * 32 + (lane >> 4) * 8;
  u16 tmp[8];
#pragma unroll
  for (int j = 0; j < 8; ++j) tmp[j] = f2bf(w[(size_t)(k0 + j) * 1536 + n]);
  *(s16x8*)&pw[(size_t)id * 8] = *(const s16x8*)tmp;
}

// ---------------- fused window kernel (two-pass proj, <=128 VGPR target) ----------------
// 1 block = 1 window (2048 blocks), 512 thr = 8 waves, wave w owns heads {2w, 2w+1}.
// LDS: x-window [64][512] bf16 (64KB, chunk-swizzled) + per-wave 8KB scratch.
__global__ __launch_bounds__(512, 2)
void k_winqkv(const u16* __restrict__ xb, const u16* __restrict__ PW,
              const float* __restrict__ qkv_b, const float* __restrict__ mask,
              const float* __restrict__ btab, u16* __restrict__ AO2) {
  __shared__ u16 lds[65536];  // 128 KiB
  const int tid = threadIdx.x;
  const int lane = tid & 63, wid = tid >> 6;
  const int quad = lane >> 4, col_l = lane & 15;
  const int win = blockIdx.x;
  const int nimg = win >> 6, a = (win >> 3) & 7, b = win & 7;

  // ---- stage x-window: row = g*8+wid, chunk = lane, src chunk pre-swizzled ^ wid
#pragma unroll
  for (int g = 0; g < 8; ++g) {
    const int h = a * 8 + g, w = b * 8 + wid;
    const size_t m = (size_t)nimg * 4096 + h * 64 + w;
    gload16(xb + m * 512 + ((lane ^ wid) * 8), &lds[(g * 512 + tid) * 8]);
  }
  asm volatile("s_waitcnt vmcnt(0)" ::: "memory");
  BARRIER();

  u16* sq = &lds[32768 + wid * 4096];  // Q [64][32] swizzled
  u16* sk = sq + 2048;                 // K [64][32] swizzled
  u16* sp = sq;                        // P [64][64] swizzled (overlays Q+K)

  const float scale = 0.17677669529663687f;  // 1/sqrt(32)
  const float* mrow = mask + (size_t)(a * 8 + b) * 4096;

  // A-fragment loader from the x-window in LDS
#define AFRAG(afv, kt)                                                           \
  {                                                                              \
    _Pragma("unroll")                                                            \
    for (int mf = 0; mf < 4; ++mf)                                               \
      afv[mf] = *(const s16x8*)&lds[(mf * 16 + col_l) * 512 +                    \
                                    ((((kt) * 4 + quad) ^ (col_l & 7)) * 8)];    \
  }

#pragma unroll 1
  for (int hh = 0; hh < 2; ++hh) {
    const int head = wid * 2 + hh;
    const u16* bpq = PW + (size_t)(head * 3 * 2) * 8192;  // q0,q1,k0,k1 contiguous

    // ======== PASS A: Q,K projection (acc 64 regs) ========
    {
      f32x4 aqk[4][4] = {};
#pragma unroll 1
      for (int kt = 0; kt < 16; ++kt) {
        s16x8 bf[4], af[4];
#pragma unroll
        for (int nf = 0; nf < 4; ++nf)
          bf[nf] = *(const s16x8*)&bpq[(size_t)nf * 8192 + kt * 512 + lane * 8];
        AFRAG(af, kt);
#pragma unroll
        for (int mf = 0; mf < 4; ++mf)
#pragma unroll
          for (int nf = 0; nf < 4; ++nf)
            aqk[mf][nf] = mfma16(af[mf], bf[nf], aqk[mf][nf]);
      }
      const float qb0 = qkv_b[head * 32 + col_l],       qb1 = qkv_b[head * 32 + 16 + col_l];
      const float kb0 = qkv_b[512 + head * 32 + col_l], kb1 = qkv_b[512 + head * 32 + 16 + col_l];
      // write Q (scaled+bias), K (bias) to scratch: [e][d], chunk ^= (e>>1)&3
#pragma unroll
      for (int r = 0; r < 4; ++r)
#pragma unroll
        for (int half = 0; half < 2; ++half)
#pragma unroll
          for (int i = 0; i < 4; ++i) {
            const int e = r * 16 + quad * 4 + i;
            const int d = half * 16 + col_l;
            const int sw = (((d >> 3) ^ ((e >> 1) & 3)) << 3) + (d & 7);
            sq[e * 32 + sw] = f2bf((aqk[r][half][i] + (half ? qb1 : qb0)) * scale);
            sk[e * 32 + sw] = f2bf(aqk[r][2 + half][i] + (half ? kb1 : kb0));
          }
    }

    // ======== S = Q K^T ========
    float rinv[4][4];
    {
      s16x8 aq[4], bk[4];
      const int ssw = (quad ^ ((col_l >> 1) & 3)) << 3;
#pragma unroll
      for (int t = 0; t < 4; ++t) {
        aq[t] = *(const s16x8*)&sq[(t * 16 + col_l) * 32 + ssw];
        bk[t] = *(const s16x8*)&sk[(t * 16 + col_l) * 32 + ssw];
      }
      f32x4 s[4][4] = {};
#pragma unroll
      for (int r = 0; r < 4; ++r)
#pragma unroll
        for (int c = 0; c < 4; ++c)
          s[r][c] = mfma16(aq[r], bk[c], s[r][c]);

      // bias + mask
#pragma unroll
      for (int r = 0; r < 4; ++r)
#pragma unroll
        for (int c = 0; c < 4; ++c)
#pragma unroll
          for (int i = 0; i < 4; ++i) {
            const int row = r * 16 + quad * 4 + i, col = c * 16 + col_l;
            const int dh = (row >> 3) - (col >> 3) + 7;
            const int dw = (row & 7) - (col & 7) + 7;
            s[r][c][i] += btab[(dh * 15 + dw) * 16 + head] + mrow[row * 64 + col];
          }

      // softmax (deferred 1/sum)
#pragma unroll
      for (int r = 0; r < 4; ++r) {
#pragma unroll
        for (int i = 0; i < 4; ++i) {
          float mx = fmaxf(fmaxf(s[r][0][i], s[r][1][i]), fmaxf(s[r][2][i], s[r][3][i]));
          mx = fmaxf(mx, __shfl_xor(mx, 1));
          mx = fmaxf(mx, __shfl_xor(mx, 2));
          mx = fmaxf(mx, __shfl_xor(mx, 4));
          mx = fmaxf(mx, __shfl_xor(mx, 8));
          float sum = 0.f;
#pragma unroll
          for (int c = 0; c < 4; ++c) {
            float p = __expf(s[r][c][i] - mx);
            s[r][c][i] = p;
            sum += p;
          }
          sum += __shfl_xor(sum, 1);
          sum += __shfl_xor(sum, 2);
          sum += __shfl_xor(sum, 4);
          sum += __shfl_xor(sum, 8);
          rinv[r][i] = 1.0f / sum;
        }
      }

      // P -> scratch (overlays Q+K; both consumed)
#pragma unroll
      for (int r = 0; r < 4; ++r)
#pragma unroll
        for (int c = 0; c < 4; ++c)
#pragma unroll
          for (int i = 0; i < 4; ++i) {
            const int row = r * 16 + quad * 4 + i, col = c * 16 + col_l;
            sp[(row * 64 + col) ^ ((row & 7) << 3)] = f2bf(s[r][c][i]);
          }
    }

    // ======== PASS B: V projection (acc 32 regs) ========
    s16x8 bv[2][2];
    {
      f32x4 av[4][2] = {};
      const u16* bpv = PW + (size_t)((head * 3 + 2) * 2) * 8192;
#pragma unroll 1
      for (int kt = 0; kt < 16; ++kt) {
        s16x8 bf[2], af[4];
#pragma unroll
        for (int nf = 0; nf < 2; ++nf)
          bf[nf] = *(const s16x8*)&bpv[(size_t)nf * 8192 + kt * 512 + lane * 8];
        AFRAG(af, kt);
#pragma unroll
        for (int mf = 0; mf < 4; ++mf)
#pragma unroll
          for (int nf = 0; nf < 2; ++nf)
            av[mf][nf] = mfma16(af[mf], bf[nf], av[mf][nf]);
      }
      const float vb0 = qkv_b[1024 + head * 32 + col_l];
      const float vb1 = qkv_b[1024 + head * 32 + 16 + col_l];
      // V: C-frag -> PV B-frag purely in registers (cross-quad shuffle)
#pragma unroll
      for (int cf = 0; cf < 2; ++cf) {
        const float vb = cf ? vb1 : vb0;
#pragma unroll
        for (int ks = 0; ks < 2; ++ks) {
          const int rA = ks * 2, rB = ks * 2 + 1;
          u32 A0 = pk2(av[rA][cf][0] + vb, av[rA][cf][1] + vb);
          u32 A1 = pk2(av[rA][cf][2] + vb, av[rA][cf][3] + vb);
          u32 B0 = pk2(av[rB][cf][0] + vb, av[rB][cf][1] + vb);
          u32 B1 = pk2(av[rB][cf][2] + vb, av[rB][cf][3] + vb);
          const int l0 = ((quad * 2) & 3) * 16 + col_l;
          const int l1 = ((quad * 2 + 1) & 3) * 16 + col_l;
          u32 a0 = (u32)__shfl((int)A0, l0), a1 = (u32)__shfl((int)A1, l0);
          u32 a2 = (u32)__shfl((int)A0, l1), a3 = (u32)__shfl((int)A1, l1);
          u32 b0 = (u32)__shfl((int)B0, l0), b1 = (u32)__shfl((int)B1, l0);
          u32 b2 = (u32)__shfl((int)B0, l1), b3 = (u32)__shfl((int)B1, l1);
          u32x4 wv;
          if (quad < 2) { wv[0] = a0; wv[1] = a1; wv[2] = a2; wv[3] = a3; }
          else          { wv[0] = b0; wv[1] = b1; wv[2] = b2; wv[3] = b3; }
          bv[cf][ks] = __builtin_bit_cast(s16x8, wv);
        }
      }
    }

    // ======== O = P V ========
    f32x4 o[4][2] = {};
#pragma unroll
    for (int r = 0; r < 4; ++r) {
#pragma unroll
      for (int ks = 0; ks < 2; ++ks) {
        const int row = r * 16 + col_l;
        s16x8 pa = *(const s16x8*)&sp[(row * 64 + ks * 32 + quad * 8) ^ ((row & 7) << 3)];
#pragma unroll
        for (int cf = 0; cf < 2; ++cf)
          o[r][cf] = mfma16(pa, bv[cf][ks], o[r][cf]);
      }
    }

    // ======== normalize + 4x4 shuffle transpose -> scratch -> 16B coalesced AO2 ========
    u16* so = sp;  // P consumed; reuse first 4KB
#pragma unroll
    for (int r = 0; r < 4; ++r) {
#pragma unroll
      for (int cf = 0; cf < 2; ++cf) {
        float v0 = o[r][cf][0] * rinv[r][0], v1 = o[r][cf][1] * rinv[r][1];
        float v2 = o[r][cf][2] * rinv[r][2], v3 = o[r][cf][3] * rinv[r][3];
        float sA = (lane & 1) ? v0 : v1; sA = __shfl_xor(sA, 1);
        float sB = (lane & 1) ? v2 : v3; sB = __shfl_xor(sB, 1);
        u32 pa_, pb_;
        if (lane & 1) { pa_ = pk2(sA, v1); pb_ = pk2(sB, v3); }
        else          { pa_ = pk2(v0, sA); pb_ = pk2(v2, sB); }
        u32 s2 = (lane & 2) ? pa_ : pb_;
        s2 = (u32)__shfl_xor((int)s2, 2);
        u32x2 val;
        if (lane & 2) { val.x = s2;  val.y = pb_; }
        else          { val.x = pa_; val.y = s2;  }
        const int e = r * 16 + quad * 4 + (col_l & 3);
        *(u32x2*)&so[e * 32 + cf * 16 + (col_l & ~3)] = val;
      }
    }
    const size_t obase = ((size_t)win * 16 + head) * 2048;
#pragma unroll
    for (int it = 0; it < 4; ++it) {
      const int e = it * 16 + (lane >> 2);
      const int dd = (lane & 3) * 8;
      *(s16x8*)&AO2[obase + e * 32 + dd] = *(const s16x8*)&so[e * 32 + dd];
    }
  }
#undef AFRAG
}

// ---------------- GEMM2: 256x256 tile, BK=64, 8 waves, 8-phase; A gathered from AO2 ----------------
__global__ __launch_bounds__(512, 2)
void k_gemm2(const u16* __restrict__ AO2, const u16* __restrict__ B,
             const float* __restrict__ bias, float* __restrict__ Out) {
  __shared__ u16 lds[65536];
  u16* ldsA = lds;
  u16* ldsB = lds + 32768;
  const int tid = threadIdx.x;
  const int lane = tid & 63, wid = tid >> 6;
  const int quad = lane >> 4, col_l = lane & 15;
  const int wr = wid >> 2, wc = wid & 3;
  const int ntn = 2;

  const int cpx = gridDim.x >> 3;
  const int sb = (blockIdx.x & 7) * cpx + (blockIdx.x >> 3);
  const int mt = sb / ntn, nt = sb - mt * ntn;
  const int m0 = mt * 256, n0 = nt * 256;

  const int srow = tid >> 3;
  const int sch = (tid & 7) ^ (srow & 7);
  const size_t gB = (size_t)(n0 + srow) * 512 + sch * 8;

  size_t baseA[4];
#pragma unroll
  for (int g = 0; g < 4; ++g) {
    const int m = m0 + g * 64 + srow;
    const int nimg = m >> 12, h = (m >> 6) & 63, w = m & 63;
    const int win = nimg * 64 + (h >> 3) * 8 + (w >> 3);
    const int e = (h & 7) * 8 + (w & 7);
    baseA[g] = ((size_t)(win * 16 + (sch >> 2)) * 64 + e) * 32 + (sch & 3) * 8;
  }

  auto STAGE = [&](int s) {
    const int bb = s & 1;
    const size_t k = (size_t)s * 64;
#pragma unroll
    for (int g = 0; g < 4; ++g) {
      gload16(AO2 + baseA[g] + (size_t)s * 4096, &ldsA[bb * 16384 + g * 4096 + tid * 8]);
      gload16(B + gB + (size_t)g * 32768 + k, &ldsB[bb * 16384 + g * 4096 + tid * 8]);
    }
  };

  STAGE(0);
  STAGE(1);
  asm volatile("s_waitcnt vmcnt(8)" ::: "memory");
  BARRIER();

  const int xsw = (col_l & 7) << 3;
  const int aRB = (wr * 128 + col_l) * 64;
  const int bRB = (wc * 64 + col_l) * 64;

  f32x4 acc[8][4] = {};

  for (int t = 0; t < 8; ++t) {
    const int base = (t & 1) * 16384;
    s16x8 a0[4], a1[4], bfr[4][2];

#pragma unroll
    for (int r = 0; r < 4; ++r)
      a0[r] = *(const s16x8*)&ldsA[base + aRB + r * 1024 + ((quad * 8) ^ xsw)];
#pragma unroll
    for (int c = 0; c < 4; ++c)
      bfr[c][0] = *(const s16x8*)&ldsB[base + bRB + c * 1024 + ((quad * 8) ^ xsw)];
    BARRIER();
    __builtin_amdgcn_s_setprio(1);
#pragma unroll
    for (int r = 0; r < 4; ++r)
#pragma unroll
      for (int c = 0; c < 4; ++c)
        acc[r][c] = mfma16(a0[r], bfr[c][0], acc[r][c]);
    __builtin_amdgcn_s_setprio(0);
    BARRIER();

#pragma unroll
    for (int r = 0; r < 4; ++r)
      a1[r] = *(const s16x8*)&ldsA[base + aRB + r * 1024 + ((32 + quad * 8) ^ xsw)];
#pragma unroll
    for (int c = 0; c < 4; ++c)
      bfr[c][1] = *(const s16x8*)&ldsB[base + bRB + c * 1024 + ((32 + quad * 8) ^ xsw)];
    BARRIER();
    __builtin_amdgcn_s_setprio(1);
#pragma unroll
    for (int r = 0; r < 4; ++r)
#pragma unroll
      for (int c = 0; c < 4; ++c)
        acc[r][c] = mfma16(a1[r], bfr[c][1], acc[r][c]);
    __builtin_amdgcn_s_setprio(0);
    BARRIER();

#pragma unroll
    for (int r = 0; r < 4; ++r)
      a0[r] = *(const s16x8*)&ldsA[base + aRB + (r + 4) * 1024 + ((quad * 8) ^ xsw)];
    BARRIER();
    __builtin_amdgcn_s_setprio(1);
#pragma unroll
    for (int r = 0; r < 4; ++r)
#pragma unroll
      for (int c = 0; c < 4; ++c)
        acc[r + 4][c] = mfma16(a0[r], bfr[c][0], acc[r + 4][c]);
    __builtin_amdgcn_s_setprio(0);
    BARRIER();

#pragma unroll
    for (int r = 0; r < 4; ++r)
      a1[r] = *(const s16x8*)&ldsA[base + aRB + (r + 4) * 1024 + ((32 + quad * 8) ^ xsw)];
    if (t < 6) STAGE(t + 2);
    BARRIER();
    __builtin_amdgcn_s_setprio(1);
#pragma unroll
    for (int r = 0; r < 4; ++r)
#pragma unroll
      for (int c = 0; c < 4; ++c)
        acc[r + 4][c] = mfma16(a1[r], bfr[c][1], acc[r + 4][c]);
    __builtin_amdgcn_s_setprio(0);
    if (t < 6)       asm volatile("s_waitcnt vmcnt(8)" ::: "memory");
    else if (t == 6) asm volatile("s_waitcnt vmcnt(0)" ::: "memory");
    BARRIER();
  }

  // fp32 epilogue: two 128-row passes through LDS
#pragma unroll
  for (int p = 0; p < 2; ++p) {
    if (p) __syncthreads();
#pragma unroll
    for (int c = 0; c < 4; ++c) {
      const float bv = bias[n0 + wc * 64 + c * 16 + col_l];
#pragma unroll
      for (int rr = 0; rr < 4; ++rr) {
        const int r = p * 4 + rr;
        float v0 = acc[r][c][0] + bv, v1 = acc[r][c][1] + bv;
        float v2 = acc[r][c][2] + bv, v3 = acc[r][c][3] + bv;
        float sA = (lane & 1) ? v0 : v1; sA = __shfl_xor(sA, 1);
        float sB = (lane & 1) ? v2 : v3; sB = __shfl_xor(sB, 1);
        float A0, A1, B0, B1;
        if (lane & 1) { A0 = sA; A1 = v1; B0 = sB; B1 = v3; }
        else          { A0 = v0; A1 = sA; B0 = v2; B1 = sB; }
        float t0 = (lane & 2) ? A0 : B0; t0 = __shfl_xor(t0, 2);
        float t1 = (lane & 2) ? A1 : B1; t1 = __shfl_xor(t1, 2);
        f32x4 outv;
        if (lane & 2) { outv[0] = t0; outv[1] = t1; outv[2] = B0; outv[3] = B1; }
        else          { outv[0] = A0; outv[1] = A1; outv[2] = t0; outv[3] = t1; }
        const int lr = wr * 64 + rr * 16 + quad * 4 + (col_l & 3);
        const int ck = (wc * 64 + c * 16 + (col_l & ~3)) >> 2;
        *(f32x4*)((char*)lds + lr * 1024 + ((ck ^ (lr & 7)) << 4)) = outv;
      }
    }
    __syncthreads();
#pragma unroll
    for (int it = 0; it < 16; ++it) {
      const int lr = wid * 16 + it;
      f32x4 v = *(const f32x4*)((char*)lds + lr * 1024 + (((int)lane ^ (lr & 7)) << 4));
      const int m = m0 + (lr >> 6) * 128 + p * 64 + (lr & 63);
      *(f32x4*)&Out[(size_t)m * 512 + n0 + lane * 4] = v;
    }
  }
}

// ---------------- launch ----------------
extern "C" void kernel_launch(void* const* d_in, const int* in_sizes, int n_in,
                              void* d_out, int out_size, void* d_ws, size_t ws_size,
                              hipStream_t stream) {
  const float* x     = (const float*)d_in[0];
  const float* mask  = (const float*)d_in[1];
  const float* qkv_w = (const float*)d_in[2];
  const float* qkv_b = (const float*)d_in[3];
  const float* out_w = (const float*)d_in[4];
  const float* out_b = (const float*)d_in[5];
  const float* btab  = (const float*)d_in[6];

  char* ws = (char*)d_ws;
  u16* xb  = (u16*)ws;                          // 134,217,728 B (x bf16)
  u16* ao2 = (u16*)(ws + 134217728);            // 134,217,728 B (attn out, blocked)
  u16* pw  = (u16*)(ws + 268435456);            // 1,572,864 B (packed qkv_w)
  u16* woT = (u16*)(ws + 270008320);            // 524,288 B

  k_conv_x<<<65536, 256, 0, stream>>>(x, xb, 16777216);
  k_pack_wqkv<<<384, 256, 0, stream>>>(qkv_w, pw);
  k_transpose_w<<<1024, 256, 0, stream>>>(out_w, woT, 512, 512);
  k_winqkv<<<2048, 512, 0, stream>>>(xb, pw, qkv_b, mask, btab, ao2);
  k_gemm2<<<1024, 512, 0, stream>>>(ao2, woT, out_b, (float*)d_out);
}

// Round 9
// 704.678 us; speedup vs baseline: 2.2300x; 1.8851x over previous
//
#include <hip/hip_runtime.h>
#include <hip/hip_bf16.h>
#include <stdint.h>

// Swin windowed MHA: N=32, H=W=64, C=512, heads=16, head_dim=32, window 8x8 (E=64).
// conv x->bf16 ; transpose weights ; GEMM1 (128^2 tile, BK=32, 4 waves, 4 blocks/CU,
// scatter epilogue to Q/K/VT via LDS transpose) ; windowed attn ; GEMM2 (same structure).

typedef __attribute__((ext_vector_type(4))) float  f32x4;
typedef __attribute__((ext_vector_type(4))) float  fvec4;
typedef __attribute__((ext_vector_type(8))) short  s16x8;
typedef __attribute__((ext_vector_type(8))) __bf16 bf16x8;
typedef __attribute__((ext_vector_type(2))) unsigned int u32x2;
typedef unsigned short u16;
typedef unsigned int   u32;
typedef __attribute__((ext_vector_type(4))) u16 u16x4;

__device__ __forceinline__ u16 f2bf(float f) {
  u32 u = __builtin_bit_cast(u32, f);
  u32 r = (u + 0x7FFFu + ((u >> 16) & 1u)) >> 16;
  return (u16)r;
}
__device__ __forceinline__ u32 pk2(float x, float y) {
  return (u32)f2bf(x) | ((u32)f2bf(y) << 16);
}

__device__ __forceinline__ f32x4 mfma16(s16x8 a, s16x8 b, f32x4 c) {
  return __builtin_amdgcn_mfma_f32_16x16x32_bf16((bf16x8)a, (bf16x8)b, c, 0, 0, 0);
}

__device__ __forceinline__ void gload16(const u16* g, u16* l) {
  __builtin_amdgcn_global_load_lds(
      (const __attribute__((address_space(1))) u32*)g,
      (__attribute__((address_space(3))) u32*)l, 16, 0, 0);
}

#define BARRIER() asm volatile("s_barrier" ::: "memory")
#define WAITVM(n) asm volatile("s_waitcnt vmcnt(" #n ")" ::: "memory")

// ---------------- conversion kernels ----------------
__global__ void k_conv_x(const float* __restrict__ x, u16* __restrict__ xb, int n4) {
  int i = blockIdx.x * 256 + threadIdx.x;
  if (i >= n4) return;
  fvec4 v = ((const fvec4*)x)[i];
  u16x4 o;
  o.x = f2bf(v.x); o.y = f2bf(v.y); o.z = f2bf(v.z); o.w = f2bf(v.w);
  ((u16x4*)xb)[i] = o;
}

__global__ void k_transpose_w(const float* __restrict__ w, u16* __restrict__ wt, int K, int N) {
  int i = blockIdx.x * 256 + threadIdx.x;
  if (i >= K * N) return;
  int k = i / N, n = i - k * N;
  wt[n * K + k] = f2bf(w[i]);
}

// ---------------- GEMM: 128x128 tile, BK=32, 4 waves, dbuf, 4 blocks/CU ----------------
// A [M][512], B [N][512] bf16 row-major. MODE 0: qkv -> scatter Q/K/VT. MODE 1: fp32 Out.
// LDS 32 KiB: A dbuf 2x8KB + B dbuf 2x8KB, reused as C-tile in the epilogue.
// LDS chunk swizzle: 16B-chunk pos ^= (row>>1)&3 (2-way max on b128 reads).
template <int MODE>
__global__ __launch_bounds__(256, 4)
void k_gemm(const u16* __restrict__ A, const u16* __restrict__ B,
            const float* __restrict__ bias,
            u16* __restrict__ Qb, u16* __restrict__ Kb, u16* __restrict__ VT,
            float* __restrict__ Out, int ntn) {
  __shared__ u16 lds[16384];        // 32 KiB
  u16* ldsA = lds;                  // [2][4096]
  u16* ldsB = lds + 8192;           // [2][4096]
  const int tid = threadIdx.x;
  const int lane = tid & 63, wid = tid >> 6;
  const int quad = lane >> 4, col_l = lane & 15;
  const int wr = wid >> 1, wc = wid & 1;   // 2x2 waves, wave tile 64x64

  const int cpx = gridDim.x >> 3;
  const int sb = (blockIdx.x & 7) * cpx + (blockIdx.x >> 3);
  const int mt = sb / ntn, nt = sb - mt * ntn;
  const int m0 = mt * 128, n0 = nt * 128;

  // staging: chunk q in {tid, tid+256}; row=q>>2, pos=q&3; src chunk = pos^((row>>1)&3).
  // (row+64 has the same swizzle since 32 ≡ 0 mod 4.)
  const int sr = tid >> 2, sp_ = tid & 3;
  const size_t gA = (size_t)(m0 + sr) * 512 + (sp_ ^ ((sr >> 1) & 3)) * 8;
  const size_t gB = (size_t)(n0 + sr) * 512 + (sp_ ^ ((sr >> 1) & 3)) * 8;

  auto STAGE = [&](int s) {
    const int b = (s & 1) * 4096;
    const int k = s * 32;
    gload16(A + gA + k, &ldsA[b + tid * 8]);
    gload16(A + gA + 64 * 512 + k, &ldsA[b + 2048 + tid * 8]);
    gload16(B + gB + k, &ldsB[b + tid * 8]);
    gload16(B + gB + 64 * 512 + k, &ldsB[b + 2048 + tid * 8]);
  };

  STAGE(0);
  f32x4 acc[4][4] = {};

  for (int kt = 0; kt < 16; ++kt) {
    const int bu = (kt & 1) * 4096;
    if (kt < 15) { STAGE(kt + 1); WAITVM(4); }
    else         { WAITVM(0); }
    BARRIER();
    s16x8 af[4], bf[4];
#pragma unroll
    for (int mf = 0; mf < 4; ++mf) {
      const int row = wr * 64 + mf * 16 + col_l;
      af[mf] = *(const s16x8*)&ldsA[bu + row * 32 + ((quad ^ ((row >> 1) & 3)) * 8)];
    }
#pragma unroll
    for (int nf = 0; nf < 4; ++nf) {
      const int row = wc * 64 + nf * 16 + col_l;
      bf[nf] = *(const s16x8*)&ldsB[bu + row * 32 + ((quad ^ ((row >> 1) & 3)) * 8)];
    }
    __builtin_amdgcn_s_setprio(1);
#pragma unroll
    for (int mf = 0; mf < 4; ++mf)
#pragma unroll
      for (int nf = 0; nf < 4; ++nf)
        acc[mf][nf] = mfma16(af[mf], bf[nf], acc[mf][nf]);
    __builtin_amdgcn_s_setprio(0);
    BARRIER();
  }

  // ---- epilogue via LDS (dbuf dead) ----
  const int hb0 = (m0 >> 6) & 63;     // even
  const int nimg = m0 >> 12;
  const int headbase = (n0 >> 5) & 15;

  if (MODE == 0) {
    const int which = n0 >> 9;        // 0=Q, 1=K, 2=V
    if (which < 2) {
      // [m][128] u16, chunk ^= m&7; 4x4 lane transpose -> 8B writes
      float bv[4];
#pragma unroll
      for (int c = 0; c < 4; ++c) bv[c] = bias[n0 + wc * 64 + c * 16 + col_l];
#pragma unroll
      for (int r = 0; r < 4; ++r) {
#pragma unroll
        for (int c = 0; c < 4; ++c) {
          float v0 = acc[r][c][0] + bv[c], v1 = acc[r][c][1] + bv[c];
          float v2 = acc[r][c][2] + bv[c], v3 = acc[r][c][3] + bv[c];
          float sA = (lane & 1) ? v0 : v1; sA = __shfl_xor(sA, 1);
          float sB = (lane & 1) ? v2 : v3; sB = __shfl_xor(sB, 1);
          u32 a, b;
          if (lane & 1) { a = pk2(sA, v1); b = pk2(sB, v3); }
          else          { a = pk2(v0, sA); b = pk2(v2, sB); }
          u32 s2 = (lane & 2) ? a : b;
          s2 = (u32)__shfl_xor((int)s2, 2);
          u32x2 val;
          if (lane & 2) { val.x = s2; val.y = b; }
          else          { val.x = a;  val.y = s2; }
          const int m = wr * 64 + r * 16 + quad * 4 + (col_l & 3);
          const int nc = wc * 64 + c * 16 + (col_l & ~3);
          *(u32x2*)&lds[m * 128 + (((nc >> 3) ^ (m & 7)) * 8) + ((nc >> 2) & 1) * 4] = val;
        }
      }
      __syncthreads();
      u16* dst = (which == 0) ? Qb : Kb;
#pragma unroll
      for (int it = 0; it < 8; ++it) {
        const int hh = (tid >> 7) & 1, wl = (tid >> 4) & 7;
        const int head_l = (tid >> 2) & 3, dch = tid & 3;
        const int m_loc = hh * 64 + it * 8 + wl;
        s16x8 val = *(const s16x8*)&lds[m_loc * 128 + (((head_l * 4 + dch) ^ (m_loc & 7)) * 8)];
        const int win = nimg * 64 + (hb0 >> 3) * 8 + it;
        const int e = ((hb0 & 7) + hh) * 8 + wl;
        const int head = headbase + head_l;
        *(s16x8*)&dst[(((size_t)win * 16 + head) * 64 + e) * 32 + dch * 8] = val;
      }
    } else {
      // V: [n][128] u16 (transposed), direct 8B writes, chunk ^= n&7
#pragma unroll
      for (int c = 0; c < 4; ++c) {
        const float bv = bias[n0 + wc * 64 + c * 16 + col_l];
        const int n = wc * 64 + c * 16 + col_l;
#pragma unroll
        for (int r = 0; r < 4; ++r) {
          const int mloc = wr * 64 + r * 16 + quad * 4;
          u32x2 val;
          val.x = pk2(acc[r][c][0] + bv, acc[r][c][1] + bv);
          val.y = pk2(acc[r][c][2] + bv, acc[r][c][3] + bv);
          *(u32x2*)&lds[n * 128 + (((mloc >> 3) ^ (n & 7)) * 8) + ((mloc >> 2) & 1) * 4] = val;
        }
      }
      __syncthreads();
#pragma unroll
      for (int it = 0; it < 8; ++it) {
        const int head_l = it & 3, dhi = it >> 2;
        const int wb = tid & 7, hh = (tid >> 3) & 1, dlow = (tid >> 4) & 15;
        const int d = dhi * 16 + dlow;
        const int n_loc = head_l * 32 + d;
        const int chunk = hh * 8 + wb;
        s16x8 val = *(const s16x8*)&lds[n_loc * 128 + ((chunk ^ (n_loc & 7)) * 8)];
        const int win = nimg * 64 + (hb0 >> 3) * 8 + wb;
        const int head = headbase + head_l;
        const int e0 = ((hb0 & 7) + hh) * 8;
        *(s16x8*)&VT[(((size_t)win * 16 + head) * 32 + d) * 64 + e0] = val;
      }
    }
  } else {
    // MODE 1: fp32 out, two 64-row passes through LDS (f32 [64][128] = 32 KB)
#pragma unroll
    for (int p = 0; p < 2; ++p) {
      if (p) __syncthreads();
      if (wr == p) {
#pragma unroll
        for (int c = 0; c < 4; ++c) {
          const float bv = bias[n0 + wc * 64 + c * 16 + col_l];
#pragma unroll
          for (int r = 0; r < 4; ++r) {
            float v0 = acc[r][c][0] + bv, v1 = acc[r][c][1] + bv;
            float v2 = acc[r][c][2] + bv, v3 = acc[r][c][3] + bv;
            float sA = (lane & 1) ? v0 : v1; sA = __shfl_xor(sA, 1);
            float sB = (lane & 1) ? v2 : v3; sB = __shfl_xor(sB, 1);
            float A0, A1, B0, B1;
            if (lane & 1) { A0 = sA; A1 = v1; B0 = sB; B1 = v3; }
            else          { A0 = v0; A1 = sA; B0 = v2; B1 = sB; }
            float t0 = (lane & 2) ? A0 : B0; t0 = __shfl_xor(t0, 2);
            float t1 = (lane & 2) ? A1 : B1; t1 = __shfl_xor(t1, 2);
            f32x4 outv;
            if (lane & 2) { outv[0] = t0; outv[1] = t1; outv[2] = B0; outv[3] = B1; }
            else          { outv[0] = A0; outv[1] = A1; outv[2] = t0; outv[3] = t1; }
            const int lr = r * 16 + quad * 4 + (col_l & 3);
            const int ck = (wc * 64 + c * 16 + (col_l & ~3)) >> 2;
            *(f32x4*)((char*)lds + lr * 512 + ((ck ^ (lr & 7)) << 4)) = outv;
          }
        }
      }
      __syncthreads();
#pragma unroll
      for (int it = 0; it < 8; ++it) {
        const int row = it * 8 + (tid >> 5);
        const int cl = tid & 31;
        f32x4 v = *(const f32x4*)((char*)lds + row * 512 + ((cl ^ (row & 7)) << 4));
        const int m = m0 + p * 64 + row;
        *(f32x4*)&Out[(size_t)m * 512 + n0 + cl * 4] = v;
      }
    }
  }
}

// ---------------- windowed attention (r3, unchanged) ----------------
__global__ __launch_bounds__(256, 2)
void k_attn(const u16* __restrict__ Q, const u16* __restrict__ K,
            const u16* __restrict__ VT, const float* __restrict__ mask,
            const float* __restrict__ btab, u16* __restrict__ AO) {
  __shared__ u16 plds[4 * 4096];
  const int tid = threadIdx.x;
  const int wid = tid >> 6, lane = tid & 63;
  const int quad = lane >> 4, col_l = lane & 15;
  const int bid = blockIdx.x;
  const int win = bid >> 2;
  const int head = ((bid & 3) << 2) | wid;
  const int nimg = win >> 6, a = (win >> 3) & 7, b = win & 7;
  const size_t wh = (size_t)(win * 16 + head);
  const u16* qb  = Q  + wh * 2048;
  const u16* kb  = K  + wh * 2048;
  const u16* vtb = VT + wh * 2048;

  s16x8 aq[4], bk[4];
#pragma unroll
  for (int t = 0; t < 4; ++t) {
    aq[t] = *(const s16x8*)&qb[(t * 16 + col_l) * 32 + quad * 8];
    bk[t] = *(const s16x8*)&kb[(t * 16 + col_l) * 32 + quad * 8];
  }
  f32x4 s[4][4] = {};
#pragma unroll
  for (int r = 0; r < 4; ++r)
#pragma unroll
    for (int c = 0; c < 4; ++c)
      s[r][c] = mfma16(aq[r], bk[c], s[r][c]);

  const float scale = 0.17677669529663687f;  // 1/sqrt(32)
  const float* mrow = mask + (size_t)(a * 8 + b) * 4096;
#pragma unroll
  for (int r = 0; r < 4; ++r)
#pragma unroll
    for (int c = 0; c < 4; ++c)
#pragma unroll
      for (int i = 0; i < 4; ++i) {
        const int row = r * 16 + quad * 4 + i, col = c * 16 + col_l;
        const int dh = (row >> 3) - (col >> 3) + 7;
        const int dw = (row & 7) - (col & 7) + 7;
        s[r][c][i] = s[r][c][i] * scale + btab[(dh * 15 + dw) * 16 + head] +
                     mrow[row * 64 + col];
      }

  float rinv[4][4];
#pragma unroll
  for (int r = 0; r < 4; ++r) {
#pragma unroll
    for (int i = 0; i < 4; ++i) {
      float mx = fmaxf(fmaxf(s[r][0][i], s[r][1][i]), fmaxf(s[r][2][i], s[r][3][i]));
      mx = fmaxf(mx, __shfl_xor(mx, 1));
      mx = fmaxf(mx, __shfl_xor(mx, 2));
      mx = fmaxf(mx, __shfl_xor(mx, 4));
      mx = fmaxf(mx, __shfl_xor(mx, 8));
      float sum = 0.f;
#pragma unroll
      for (int c = 0; c < 4; ++c) {
        float p = __expf(s[r][c][i] - mx);
        s[r][c][i] = p;
        sum += p;
      }
      sum += __shfl_xor(sum, 1);
      sum += __shfl_xor(sum, 2);
      sum += __shfl_xor(sum, 4);
      sum += __shfl_xor(sum, 8);
      rinv[r][i] = 1.0f / sum;
    }
  }

  u16* pl = &plds[wid * 4096];
#pragma unroll
  for (int r = 0; r < 4; ++r)
#pragma unroll
    for (int c = 0; c < 4; ++c)
#pragma unroll
      for (int i = 0; i < 4; ++i) {
        const int row = r * 16 + quad * 4 + i, col = c * 16 + col_l;
        const int off = (row * 128 + col * 2) ^ ((row & 7) << 4);
        *(u16*)((char*)pl + off) = f2bf(s[r][c][i]);
      }
  __syncthreads();

  s16x8 bv[2][2];
#pragma unroll
  for (int c2 = 0; c2 < 2; ++c2)
#pragma unroll
    for (int ks = 0; ks < 2; ++ks)
      bv[c2][ks] = *(const s16x8*)&vtb[(c2 * 16 + col_l) * 64 + ks * 32 + quad * 8];

  f32x4 o[4][2] = {};
#pragma unroll
  for (int r = 0; r < 4; ++r) {
#pragma unroll
    for (int ks = 0; ks < 2; ++ks) {
      const int row = r * 16 + col_l;
      const int off = (row * 128 + (ks * 32 + quad * 8) * 2) ^ ((row & 7) << 4);
      s16x8 pa = *(const s16x8*)((char*)pl + off);
#pragma unroll
      for (int c2 = 0; c2 < 2; ++c2)
        o[r][c2] = mfma16(pa, bv[c2][ks], o[r][c2]);
    }
  }

#pragma unroll
  for (int r = 0; r < 4; ++r) {
#pragma unroll
    for (int i = 0; i < 4; ++i) {
      const int row = r * 16 + quad * 4 + i;
      const int h = a * 8 + (row >> 3), w = b * 8 + (row & 7);
      const size_t m = (size_t)nimg * 4096 + (size_t)h * 64 + w;
      const float inv = rinv[r][i];
#pragma unroll
      for (int c2 = 0; c2 < 2; ++c2)
        AO[m * 512 + head * 32 + c2 * 16 + col_l] = f2bf(o[r][c2][i] * inv);
    }
  }
}

// ---------------- launch ----------------
extern "C" void kernel_launch(void* const* d_in, const int* in_sizes, int n_in,
                              void* d_out, int out_size, void* d_ws, size_t ws_size,
                              hipStream_t stream) {
  const float* x     = (const float*)d_in[0];
  const float* mask  = (const float*)d_in[1];
  const float* qkv_w = (const float*)d_in[2];
  const float* qkv_b = (const float*)d_in[3];
  const float* out_w = (const float*)d_in[4];
  const float* out_b = (const float*)d_in[5];
  const float* btab  = (const float*)d_in[6];

  char* ws = (char*)d_ws;
  u16* xb    = (u16*)ws;                        // 134,217,728 B (x bf16, reused as attn_out)
  u16* vt    = (u16*)(ws + 134217728);          // 134,217,728 B (V^T)
  u16* wqkvT = (u16*)(ws + 268435456);          // 1,572,864 B
  u16* woT   = (u16*)(ws + 270008320);          // 524,288 B

  u16* Qb = (u16*)d_out;                        // 134,217,728 B
  u16* Kb = (u16*)d_out + 67108864;             // 134,217,728 B

  k_conv_x<<<65536, 256, 0, stream>>>(x, xb, 16777216);
  k_transpose_w<<<3072, 256, 0, stream>>>(qkv_w, wqkvT, 512, 1536);
  k_transpose_w<<<1024, 256, 0, stream>>>(out_w, woT, 512, 512);
  k_gemm<0><<<12288, 256, 0, stream>>>(xb, wqkvT, qkv_b, Qb, Kb, vt, nullptr, 12);
  k_attn<<<8192, 256, 0, stream>>>(Qb, Kb, vt, mask, btab, xb);
  k_gemm<1><<<4096, 256, 0, stream>>>(xb, woT, out_b, nullptr, nullptr, nullptr,
                                      (float*)d_out, 4);
}